// Round 14
// baseline (919.654 us; speedup 1.0000x reference)
//
#include <hip/hip_runtime.h>

#define DEV __device__ __forceinline__

typedef unsigned short u16;
typedef unsigned int   u32;
typedef u16   u16x4 __attribute__((ext_vector_type(4)));
typedef u16   u16x8 __attribute__((ext_vector_type(8)));
typedef __bf16 bf16x8 __attribute__((ext_vector_type(8)));
typedef float f32x4 __attribute__((ext_vector_type(4)));

DEV float b2f(u16 u){ return __uint_as_float(((u32)u) << 16); }
DEV u16 f2b(float f){ u32 u = __float_as_uint(f); u32 r = (u + 0x7fffu + ((u >> 16) & 1u)) >> 16; return (u16)r; }

// RNE triple split: x = h + l + l2 (each bf16), residual ~2^-27 rel
DEV void split3(float x, u16& h, u16& l, u16& l2){
  u32 ub = __float_as_uint(x);
  u32 rb = ub + 0x7fffu + ((ub >> 16) & 1u);
  float hf = __uint_as_float(rb & 0xffff0000u);
  float r1 = x - hf;
  u32 u1 = __float_as_uint(r1);
  u32 rb1 = u1 + 0x7fffu + ((u1 >> 16) & 1u);
  float lf = __uint_as_float(rb1 & 0xffff0000u);
  h = (u16)(rb >> 16);
  l = (u16)(rb1 >> 16);
  l2 = f2b(r1 - lf);
}

DEV f32x4 mfma16(u16x8 a, u16x8 b, f32x4 c){
  return __builtin_amdgcn_mfma_f32_16x16x32_bf16(
      __builtin_bit_cast(bf16x8, a), __builtin_bit_cast(bf16x8, b), c, 0, 0, 0);
}

// async global->LDS 16B (wave-uniform LDS base + lane*16; LDS must be linear)
DEV void gload16(const void* g, void* l){
  __builtin_amdgcn_global_load_lds(
      (const __attribute__((address_space(1))) u32*)g,
      (__attribute__((address_space(3))) u32*)l,
      16, 0, 0);
}

// ---------------- LayerNorm: x(f32) -> xn(bf16) + per-row stats ----------------
__global__ __launch_bounds__(256) void ln_kernel(const float* __restrict__ x,
                                                 const float* __restrict__ w,
                                                 const float* __restrict__ bb,
                                                 u16* __restrict__ xn,
                                                 float2* __restrict__ stats){
  int row = blockIdx.x;
  const float* xr = x + (size_t)row * 512;
  int t = threadIdx.x;
  float2 v = *(const float2*)(xr + t * 2);
  float s = v.x + v.y;
  float sq = v.x * v.x + v.y * v.y;
  #pragma unroll
  for(int off = 32; off; off >>= 1){ s += __shfl_xor(s, off, 64); sq += __shfl_xor(sq, off, 64); }
  __shared__ float rs[4], rq[4];
  int wv = t >> 6, ln = t & 63;
  if(ln == 0){ rs[wv] = s; rq[wv] = sq; }
  __syncthreads();
  s = rs[0] + rs[1] + rs[2] + rs[3];
  sq = rq[0] + rq[1] + rq[2] + rq[3];
  float mu = s * (1.f / 512.f);
  float var = sq * (1.f / 512.f) - mu * mu;
  float rstd = rsqrtf(var + 1e-5f);
  if(t == 0) stats[row] = make_float2(mu, rstd);
  float w0 = w[t * 2], w1 = w[t * 2 + 1], b0 = bb[t * 2], b1 = bb[t * 2 + 1];
  u16 u0 = f2b((v.x - mu) * rstd * w0 + b0);
  u16 u1 = f2b((v.y - mu) * rstd * w1 + b1);
  ((u32*)(xn + (size_t)row * 512))[t] = (u32)u0 | ((u32)u1 << 16);
}

// ------------- landmark means of LN(x) in fp32: xl[b*256+j][512] -------------
__global__ __launch_bounds__(256) void xl_kernel(const float* __restrict__ x,
                                                 const float2* __restrict__ stats,
                                                 const float* __restrict__ w,
                                                 const float* __restrict__ bb,
                                                 float* __restrict__ xl){
  int blk = blockIdx.x;          // b*256 + j
  int b = blk >> 8, j = blk & 255;
  int t = threadIdx.x;
  int d0 = t * 2;
  float acc0 = 0.f, acc1 = 0.f;
  size_t row0 = (size_t)b * 8192 + (size_t)j * 32;
  for(int tt = 0; tt < 32; tt++){
    size_t row = row0 + tt;
    float2 st = stats[row];
    const float* xr = x + row * 512;
    float2 v = *(const float2*)(xr + d0);
    acc0 += (v.x - st.x) * st.y;
    acc1 += (v.y - st.x) * st.y;
  }
  float* dst = xl + (size_t)blk * 512;
  dst[d0]     = acc0 * (1.f / 32.f) * w[d0]     + bb[d0];
  dst[d0 + 1] = acc1 * (1.f / 32.f) * w[d0 + 1] + bb[d0 + 1];
}

// ------------- fused weight prep: wqkvT(bf16), woutT(bf16), wqkT(f32) -------------
__global__ __launch_bounds__(256) void prep_weights(const float* __restrict__ w_qkv,
                                                    const float* __restrict__ w_out,
                                                    u16* __restrict__ wqkvT,
                                                    u16* __restrict__ woutT,
                                                    float* __restrict__ wqkT){
  int idx = blockIdx.x * 256 + threadIdx.x;
  if(idx < 786432){
    int k = idx / 1536, n = idx - k * 1536;
    wqkvT[(size_t)n * 512 + k] = f2b(w_qkv[idx]);
  } else if(idx < 786432 + 262144){
    int i2 = idx - 786432;
    int k = i2 >> 9, n = i2 & 511;
    woutT[(size_t)n * 512 + k] = f2b(w_out[i2]);
  } else {
    int i3 = idx - 786432 - 262144;
    int n = i3 >> 9, k = i3 & 511;
    wqkT[i3] = w_qkv[(size_t)k * 1536 + n];
  }
}

// ------------- v [key][d] -> vt [d][key] (bf16, per bh) -------------
__global__ __launch_bounds__(256) void vtrans_kernel(const u16* __restrict__ v,
                                                     u16* __restrict__ vt){
  __shared__ u16 tile[64][72];
  int bh = blockIdx.y, n0 = blockIdx.x * 64;
  int t = threadIdx.x;
  for(int s = t; s < 512; s += 256){
    int row = s >> 3, col = (s & 7) * 8;
    *(u16x8*)&tile[row][col] = *(const u16x8*)(v + ((size_t)bh * 8192 + n0 + row) * 64 + col);
  }
  __syncthreads();
  for(int s = t; s < 512; s += 256){
    int d = s >> 3, nc = (s & 7) * 8;
    u16x8 u;
    #pragma unroll
    for(int e = 0; e < 8; e++) u[e] = tile[nc + e][d];
    *(u16x8*)(vt + ((size_t)bh * 64 + d) * 8192 + n0 + nc) = u;
  }
}

// ------------- big bf16 GEMM: A[M x 512] @ BT[N x 512]^T, 128x128 tile -------------
// global_load_lds staging; EPI0 uses LDS-staged coalesced u16x8 epilogue stores
template<int EPI>
__global__ __launch_bounds__(256) void gemm128(const u16* __restrict__ A,
                                               const u16* __restrict__ BT,
                                               u16* __restrict__ qo, u16* __restrict__ ko, u16* __restrict__ vo,
                                               const float* __restrict__ bout,
                                               const float* __restrict__ xres,
                                               float* __restrict__ dout){
  __shared__ union SU {
    struct { u16 A[128 * 32]; u16 B[128 * 32]; } s;
    u16 C[64][128];
  } sh;
  const int K = 512;
  int nby = gridDim.y;
  int nwg = gridDim.x * nby;
  int orig = blockIdx.y * gridDim.x + blockIdx.x;
  int cpx = nwg >> 3;
  int wg = (orig & 7) * cpx + (orig >> 3);
  int fx = wg / nby, fy = wg - fx * nby;
  int tb_m = fx * 128, tb_n = fy * 128;
  int tid = threadIdx.x, lane = tid & 63, w = tid >> 6;
  int wm = (w >> 1) * 64, wn = (w & 1) * 64;
  f32x4 acc[4][4] = {};
  int srow = tid >> 2, sk = (tid & 3) * 8;
  const u16* Ag = A + (size_t)(tb_m + srow) * K + sk;
  const u16* Bg = BT + (size_t)(tb_n + srow) * K + sk;
  u16* Al = sh.s.A + tid * 8;
  u16* Bl = sh.s.B + tid * 8;
  for(int kk = 0; kk < K; kk += 32){
    __syncthreads();
    gload16(Ag + kk, Al);
    gload16(Ag + kk + (size_t)64 * K, Al + 2048);
    gload16(Bg + kk, Bl);
    gload16(Bg + kk + (size_t)64 * K, Bl + 2048);
    __syncthreads();
    int r = lane & 15, ko2 = (lane >> 4) * 8;
    u16x8 af[4], bf[4];
    #pragma unroll
    for(int mi = 0; mi < 4; mi++) af[mi] = *(const u16x8*)&sh.s.A[(wm + mi * 16 + r) * 32 + ko2];
    #pragma unroll
    for(int ni = 0; ni < 4; ni++) bf[ni] = *(const u16x8*)&sh.s.B[(wn + ni * 16 + r) * 32 + ko2];
    #pragma unroll
    for(int mi = 0; mi < 4; mi++)
      #pragma unroll
      for(int ni = 0; ni < 4; ni++)
        acc[mi][ni] = mfma16(af[mi], bf[ni], acc[mi][ni]);
  }
  if(EPI == 0){
    // block-uniform: one t3 (128-col block inside one 512-col third), one b
    int t3 = tb_n >> 9;
    float qs = (t3 == 0) ? 0.125f : 1.f;
    u16* dst = (t3 == 0 ? qo : (t3 == 1 ? ko : vo));
    int b = tb_m >> 13;
    int lg = lane >> 4, r = lane & 15;
    #pragma unroll
    for(int phase = 0; phase < 2; phase++){
      __syncthreads();
      if((w >> 1) == phase){
        #pragma unroll
        for(int mi = 0; mi < 4; mi++)
          #pragma unroll
          for(int ni = 0; ni < 4; ni++)
            #pragma unroll
            for(int e = 0; e < 4; e++)
              sh.C[mi * 16 + lg * 4 + e][wn + ni * 16 + r] = f2b(acc[mi][ni][e] * qs);
      }
      __syncthreads();
      #pragma unroll
      for(int ps = 0; ps < 4; ps++){
        int rloc = ps * 16 + (tid >> 4);
        int row = tb_m + phase * 64 + rloc;
        int cg = (tid & 15) * 8;
        int col = tb_n + cg;
        int h = (col >> 6) & 7, dh = col & 63;
        int n = row & 8191;
        *(u16x8*)&dst[(((size_t)(b * 8 + h) * 8192) + n) * 64 + dh] = *(const u16x8*)&sh.C[rloc][cg];
      }
    }
  } else {
    int r = lane & 15, rr = (lane >> 4) * 4;
    #pragma unroll
    for(int mi = 0; mi < 4; mi++)
      #pragma unroll
      for(int ni = 0; ni < 4; ni++){
        int col = tb_n + wn + ni * 16 + r;
        #pragma unroll
        for(int e = 0; e < 4; e++){
          int row = tb_m + wm + mi * 16 + rr + e;
          float val = acc[mi][ni][e] + bout[col] + xres[(size_t)row * 512 + col];
          dout[(size_t)row * 512 + col] = val;
        }
      }
  }
}

// ------------- fp32 GEMM: ql/kl = xl @ wqkT^T, scatter epi + hi/lo split -------------
__global__ __launch_bounds__(256) void gemm_qlkl(const float* __restrict__ A,
                                                 const float* __restrict__ BT,
                                                 float* __restrict__ qlf,
                                                 float* __restrict__ klf,
                                                 u16* __restrict__ qlh, u16* __restrict__ qll,
                                                 u16* __restrict__ klh, u16* __restrict__ kll){
  __shared__ float As[64][17];
  __shared__ float Bs[64][17];
  int tb_m = blockIdx.x * 64, tb_n = blockIdx.y * 64;
  int tid = threadIdx.x;
  int ty = tid >> 4, tx = tid & 15;
  float acc[4][4] = {};
  int srow = tid >> 2, sseg = (tid & 3) * 4;
  const float* Ag = A + (size_t)(tb_m + srow) * 512 + sseg;
  const float* Bg = BT + (size_t)(tb_n + srow) * 512 + sseg;
  for(int kk = 0; kk < 512; kk += 16){
    __syncthreads();
    f32x4 a4 = *(const f32x4*)(Ag + kk);
    f32x4 b4 = *(const f32x4*)(Bg + kk);
    #pragma unroll
    for(int e = 0; e < 4; e++){ As[srow][sseg + e] = a4[e]; Bs[srow][sseg + e] = b4[e]; }
    __syncthreads();
    #pragma unroll
    for(int k2 = 0; k2 < 16; k2++){
      float a[4], b[4];
      #pragma unroll
      for(int i = 0; i < 4; i++) a[i] = As[ty * 4 + i][k2];
      #pragma unroll
      for(int jv = 0; jv < 4; jv++) b[jv] = Bs[tx * 4 + jv][k2];
      #pragma unroll
      for(int i = 0; i < 4; i++)
        #pragma unroll
        for(int jv = 0; jv < 4; jv++) acc[i][jv] += a[i] * b[jv];
    }
  }
  #pragma unroll
  for(int i = 0; i < 4; i++)
    #pragma unroll
    for(int jv = 0; jv < 4; jv++){
      int r = tb_m + ty * 4 + i;
      int c = tb_n + tx * 4 + jv;
      int b = r >> 8, jl = r & 255;
      float val = acc[i][jv];
      if(c < 512){
        float q = val * 0.125f;
        size_t qi = (((size_t)(b * 8 + (c >> 6)) * 256) + jl) * 64 + (c & 63);
        qlf[qi] = q;
        u16 hi = f2b(q);
        qlh[qi] = hi; qll[qi] = f2b(q - b2f(hi));
      } else {
        int c2 = c - 512;
        size_t ki = (((size_t)(b * 8 + (c2 >> 6)) * 256) + jl) * 64 + (c2 & 63);
        klf[ki] = val;
        u16 hi = f2b(val);
        klh[ki] = hi; kll[ki] = f2b(val - b2f(hi));
      }
    }
}

// ------------- batched pinv GEMM via bf16 triple-split MFMA -------------
__global__ __launch_bounds__(256) void gemm_pinv_mfma(
    const u16* __restrict__ Ah, const u16* __restrict__ Al, const u16* __restrict__ Al2,
    const u16* __restrict__ Bh, const u16* __restrict__ Bl, const u16* __restrict__ Bl2,
    u16* __restrict__ Ch, u16* __restrict__ Cl, u16* __restrict__ Cl2,
    float dB, int bneg, float osc){
  __shared__ u16 As_[3][64][40];   // [level][row][k]
  __shared__ u16 Bs_[3][64][40];   // [level][col][k]  (transposed tile)
  int bh = blockIdx.y;
  size_t base = (size_t)bh * 65536;
  int tb_m = (blockIdx.x >> 2) * 64, tb_n = (blockIdx.x & 3) * 64;
  int tid = threadIdx.x, lane = tid & 63, w = tid >> 6;
  int lr = lane & 15, lg = lane >> 4;
  int wm = (w >> 1) * 32, wn = (w & 1) * 32;
  f32x4 acc[2][2] = {};
  int arow = tid >> 2, akq = (tid & 3) * 8;
  int bcol = tid & 63, bkq = tid >> 6;
  u16 sx = bneg ? (u16)0x8000u : (u16)0;
  size_t aoff = base + (size_t)(tb_m + arow) * 256 + akq;
  size_t boff = base + (size_t)(tb_n + bcol);
  for(int kk = 0; kk < 256; kk += 32){
    u16x8 ra0 = *(const u16x8*)(Ah + aoff + kk);
    u16x8 ra1 = *(const u16x8*)(Al + aoff + kk);
    u16x8 ra2 = *(const u16x8*)(Al2 + aoff + kk);
    u16x8 rb0, rb1, rb2;
    #pragma unroll
    for(int j = 0; j < 8; j++){
      size_t bi = boff + (size_t)(kk + bkq * 8 + j) * 256;
      rb0[j] = Bh[bi] ^ sx;
      rb1[j] = Bl[bi] ^ sx;
      rb2[j] = Bl2[bi] ^ sx;
    }
    __syncthreads();
    *(u16x8*)&As_[0][arow][akq] = ra0;
    *(u16x8*)&As_[1][arow][akq] = ra1;
    *(u16x8*)&As_[2][arow][akq] = ra2;
    *(u16x8*)&Bs_[0][bcol][bkq * 8] = rb0;
    *(u16x8*)&Bs_[1][bcol][bkq * 8] = rb1;
    *(u16x8*)&Bs_[2][bcol][bkq * 8] = rb2;
    __syncthreads();
    u16x8 af[3][2], bf[3][2];
    #pragma unroll
    for(int v = 0; v < 3; v++)
      #pragma unroll
      for(int mi = 0; mi < 2; mi++){
        af[v][mi] = *(const u16x8*)&As_[v][wm + mi * 16 + lr][lg * 8];
        bf[v][mi] = *(const u16x8*)&Bs_[v][wn + mi * 16 + lr][lg * 8];
      }
    #pragma unroll
    for(int mi = 0; mi < 2; mi++)
      #pragma unroll
      for(int ni = 0; ni < 2; ni++){
        acc[mi][ni] = mfma16(af[1][mi], bf[1][ni], acc[mi][ni]);   // l*l
        acc[mi][ni] = mfma16(af[2][mi], bf[0][ni], acc[mi][ni]);   // l2*h
        acc[mi][ni] = mfma16(af[0][mi], bf[2][ni], acc[mi][ni]);   // h*l2
        acc[mi][ni] = mfma16(af[1][mi], bf[0][ni], acc[mi][ni]);   // l*h
        acc[mi][ni] = mfma16(af[0][mi], bf[1][ni], acc[mi][ni]);   // h*l
        acc[mi][ni] = mfma16(af[0][mi], bf[0][ni], acc[mi][ni]);   // h*h
      }
  }
  #pragma unroll
  for(int mi = 0; mi < 2; mi++)
    #pragma unroll
    for(int ni = 0; ni < 2; ni++)
      #pragma unroll
      for(int e = 0; e < 4; e++){
        int r = tb_m + wm + mi * 16 + lg * 4 + e;
        int c = tb_n + wn + ni * 16 + lr;
        size_t idx = base + (size_t)r * 256 + c;
        float arec = b2f(Ah[idx]) + b2f(Al[idx]) + b2f(Al2[idx]);
        float val = osc * (dB * arec + acc[mi][ni][e]);
        u16 h, l, l2;
        split3(val, h, l, l2);
        Ch[idx] = h; Cl[idx] = l; Cl2[idx] = l2;
      }
}

// ------------- a2 = softmax(q_l @ k_l^T) per row, fp32 + triple -------------
__global__ __launch_bounds__(256) void a2_kernel(const float* __restrict__ qlf,
                                                 const float* __restrict__ klf,
                                                 float* __restrict__ a2,
                                                 u16* __restrict__ a2h, u16* __restrict__ a2l,
                                                 u16* __restrict__ a2l2){
  int i = blockIdx.x, bh = blockIdx.y, j = threadIdx.x;
  const float* qp = qlf + ((size_t)bh * 256 + i) * 64;
  const float* kp = klf + ((size_t)bh * 256 + j) * 64;
  float s = 0.f;
  #pragma unroll
  for(int d0 = 0; d0 < 16; d0++){
    f32x4 uq = *(const f32x4*)(qp + d0 * 4);
    f32x4 uk = *(const f32x4*)(kp + d0 * 4);
    #pragma unroll
    for(int e = 0; e < 4; e++) s += uq[e] * uk[e];
  }
  __shared__ float red[256];
  red[j] = s; __syncthreads();
  for(int off = 128; off; off >>= 1){ if(j < off) red[j] = fmaxf(red[j], red[j + off]); __syncthreads(); }
  float m = red[0]; __syncthreads();
  float p = expf(s - m);
  red[j] = p; __syncthreads();
  for(int off = 128; off; off >>= 1){ if(j < off) red[j] += red[j + off]; __syncthreads(); }
  float denom = red[0];
  float vv = p / denom;
  size_t idx = ((size_t)bh * 256 + i) * 256 + j;
  a2[idx] = vv;
  u16 h, l, l2;
  split3(vv, h, l, l2);
  a2h[idx] = h; a2l[idx] = l; a2l2[idx] = l2;
}

// ------------- scale maxes -------------
__global__ __launch_bounds__(256) void scale_kernel(const float* __restrict__ a2, u32* __restrict__ maxes){
  int bh = blockIdx.x, t = threadIdx.x;
  const float* p = a2 + (size_t)bh * 65536;
  float cs = 0.f, rs = 0.f;
  for(int i = 0; i < 256; i++) cs += p[i * 256 + t];
  for(int j = 0; j < 256; j++) rs += p[t * 256 + j];
  __shared__ float rc[256], rr[256];
  rc[t] = cs; rr[t] = rs; __syncthreads();
  for(int off = 128; off; off >>= 1){
    if(t < off){ rc[t] = fmaxf(rc[t], rc[t + off]); rr[t] = fmaxf(rr[t], rr[t + off]); }
    __syncthreads();
  }
  if(t == 0){
    atomicMax(&maxes[0], __float_as_uint(rc[0]));
    atomicMax(&maxes[1], __float_as_uint(rr[0]));
  }
}

// ------------- z0 = a2^T / scale -> triple (tiled transpose) -------------
__global__ __launch_bounds__(256) void z0_kernel(const float* __restrict__ a2,
                                                 u16* __restrict__ zh, u16* __restrict__ zl,
                                                 u16* __restrict__ zl2,
                                                 const u32* __restrict__ maxes){
  __shared__ float tile[64][65];
  float inv = 1.f / (__uint_as_float(maxes[0]) * __uint_as_float(maxes[1]));
  int bh = blockIdx.z;
  int i0 = blockIdx.x * 64, j0 = blockIdx.y * 64;
  const float* src = a2 + (size_t)bh * 65536;
  size_t dbase = (size_t)bh * 65536;
  for(int s = threadIdx.x; s < 1024; s += 256){
    int r = s >> 4, c4 = (s & 15) * 4;
    f32x4 v = *(const f32x4*)(src + (size_t)(i0 + r) * 256 + j0 + c4);
    #pragma unroll
    for(int e = 0; e < 4; e++) tile[r][c4 + e] = v[e];
  }
  __syncthreads();
  for(int s = threadIdx.x; s < 1024; s += 256){
    int jr = s >> 4, c4 = (s & 15) * 4;
    u16x4 hv, lv, l2v;
    #pragma unroll
    for(int e = 0; e < 4; e++){
      float val = tile[c4 + e][jr] * inv;
      u16 h, l, l2;
      split3(val, h, l, l2);
      hv[e] = h; lv[e] = l; l2v[e] = l2;
    }
    size_t doff = dbase + (size_t)(j0 + jr) * 256 + i0 + c4;
    *(u16x4*)(zh + doff) = hv;
    *(u16x4*)(zl + doff) = lv;
    *(u16x4*)(zl2 + doff) = l2v;
  }
}

// ------------- unified MFMA flash attention, LDS-staged K/V, single-chain PV -------------
// MODE 0 (a1): A=qb exact; B=kl hi/lo; V=W hi only; 256 keys; RMW into o.  smem 45568 B
// MODE 1 (a3v): A=ql hi/lo; B=kb exact; V=v^T exact; 512-key split.        smem 36352 B
template<int MODE>
__global__ __launch_bounds__(256) void flash_kernel(
    const u16* __restrict__ Aex,
    const u16* __restrict__ Ah_, const u16* __restrict__ Al_,
    const u16* __restrict__ Bh_, const u16* __restrict__ Bl_,
    const u16* __restrict__ Vh_,
    u16* __restrict__ o,
    float* __restrict__ pacc, float* __restrict__ plo){
  extern __shared__ char smem[];
  u32 (*pbuf)[32][35] = (u32(*)[32][35])smem;                  // 17920 B; stores P-hi (low16)
  u16 (*ksh)[72] = (u16(*)[72])(smem + 17920);                 // [64][72] key-major
  u16 (*vsh)[72] = (u16(*)[72])(smem + 17920 + 9216);          // [64][72] d-major
  u16 (*ksl)[72] = (u16(*)[72])(smem + 17920 + 2 * 9216);      // MODE0 only

  int tid = threadIdx.x;
  int w = tid >> 6, lane = tid & 63;
  int lr = lane & 15, lg = lane >> 4;
  int bh = blockIdx.y;
  int rowbase = blockIdx.x * 128 + w * 32;
  constexpr int NT = (MODE == 0) ? 4 : 8;
  int kbase = (MODE == 0) ? 0 : blockIdx.z * 512;
  int srow = tid >> 2, sseg = (tid & 3) * 16;

  u16x8 afh[2][2], afl[2][2];
  #pragma unroll
  for(int mi = 0; mi < 2; mi++)
    #pragma unroll
    for(int ks = 0; ks < 2; ks++){
      int r = rowbase + mi * 16 + lr;
      if(MODE == 0){
        afh[mi][ks] = *(const u16x8*)(Aex + ((size_t)bh * 8192 + r) * 64 + ks * 32 + lg * 8);
      } else {
        size_t idx = ((size_t)bh * 256 + r) * 64 + ks * 32 + lg * 8;
        afh[mi][ks] = *(const u16x8*)(Ah_ + idx);
        afl[mi][ks] = *(const u16x8*)(Al_ + idx);
      }
    }

  f32x4 pv[2][4] = {};
  float l[2][4] = {};

  for(int t = 0; t < NT; t++){
    int koff = t * 64;
    __syncthreads();
    if(MODE == 0){
      size_t kix = ((size_t)bh * 256 + koff + srow) * 64 + sseg;
      *(u16x8*)&ksh[srow][sseg]     = *(const u16x8*)(Bh_ + kix);
      *(u16x8*)&ksh[srow][sseg + 8] = *(const u16x8*)(Bh_ + kix + 8);
      *(u16x8*)&ksl[srow][sseg]     = *(const u16x8*)(Bl_ + kix);
      *(u16x8*)&ksl[srow][sseg + 8] = *(const u16x8*)(Bl_ + kix + 8);
      size_t vix = ((size_t)bh * 64 + srow) * 256 + koff + sseg;
      *(u16x8*)&vsh[srow][sseg]     = *(const u16x8*)(Vh_ + vix);
      *(u16x8*)&vsh[srow][sseg + 8] = *(const u16x8*)(Vh_ + vix + 8);
    } else {
      size_t kix = ((size_t)bh * 8192 + kbase + koff + srow) * 64 + sseg;
      *(u16x8*)&ksh[srow][sseg]     = *(const u16x8*)(Bh_ + kix);
      *(u16x8*)&ksh[srow][sseg + 8] = *(const u16x8*)(Bh_ + kix + 8);
      size_t vix = ((size_t)bh * 64 + srow) * 8192 + kbase + koff + sseg;
      *(u16x8*)&vsh[srow][sseg]     = *(const u16x8*)(Vh_ + vix);
      *(u16x8*)&vsh[srow][sseg + 8] = *(const u16x8*)(Vh_ + vix + 8);
    }
    __syncthreads();
    #pragma unroll
    for(int half = 0; half < 2; half++){
      u16x8 bfh[2][2], bfl[2][2];
      #pragma unroll
      for(int ni = 0; ni < 2; ni++){
        int krow = half * 32 + ni * 16 + lr;
        #pragma unroll
        for(int ks = 0; ks < 2; ks++){
          bfh[ni][ks] = *(const u16x8*)&ksh[krow][ks * 32 + lg * 8];
          if(MODE == 0) bfl[ni][ks] = *(const u16x8*)&ksl[krow][ks * 32 + lg * 8];
        }
      }
      f32x4 sv[2][2];
      #pragma unroll
      for(int mi = 0; mi < 2; mi++)
        #pragma unroll
        for(int ni = 0; ni < 2; ni++) sv[mi][ni] = (f32x4){0.f, 0.f, 0.f, 0.f};
      __builtin_amdgcn_s_setprio(1);
      #pragma unroll
      for(int ks = 0; ks < 2; ks++)
        #pragma unroll
        for(int mi = 0; mi < 2; mi++)
          #pragma unroll
          for(int ni = 0; ni < 2; ni++){
            sv[mi][ni] = mfma16(afh[mi][ks], bfh[ni][ks], sv[mi][ni]);
            if(MODE == 0) sv[mi][ni] = mfma16(afh[mi][ks], bfl[ni][ks], sv[mi][ni]);
            else          sv[mi][ni] = mfma16(afl[mi][ks], bfh[ni][ks], sv[mi][ni]);
          }
      __builtin_amdgcn_s_setprio(0);
      // exp + per-lane l; store P-hi into pbuf (transpose)
      #pragma unroll
      for(int mi = 0; mi < 2; mi++)
        #pragma unroll
        for(int ni = 0; ni < 2; ni++)
          #pragma unroll
          for(int e = 0; e < 4; e++){
            float p = __expf(sv[mi][ni][e]);
            l[mi][e] += p;
            u32 pb = __float_as_uint(p);
            u32 rb = pb + 0x7fffu + ((pb >> 16) & 1u);
            pbuf[w][mi * 16 + lg * 4 + e][ni * 16 + lr] = rb >> 16;
          }
      u16x8 pah[2];
      #pragma unroll
      for(int mi = 0; mi < 2; mi++){
        u32 tv[8];
        #pragma unroll
        for(int e2 = 0; e2 < 8; e2++) tv[e2] = pbuf[w][mi * 16 + lr][lg * 8 + e2];
        u32* ph = (u32*)&pah[mi];
        #pragma unroll
        for(int q = 0; q < 4; q++)
          ph[q] = __builtin_amdgcn_perm(tv[2 * q + 1], tv[2 * q], 0x05040100u);
      }
      __builtin_amdgcn_s_setprio(1);
      #pragma unroll
      for(int ni2 = 0; ni2 < 4; ni2++){
        int d = ni2 * 16 + lr;
        u16x8 vh = *(const u16x8*)&vsh[d][half * 32 + lg * 8];
        #pragma unroll
        for(int mi = 0; mi < 2; mi++)
          pv[mi][ni2] = mfma16(pah[mi], vh, pv[mi][ni2]);
      }
      __builtin_amdgcn_s_setprio(0);
    }
  }
  #pragma unroll
  for(int mi = 0; mi < 2; mi++)
    #pragma unroll
    for(int e = 0; e < 4; e++){
      float lv = l[mi][e];
      #pragma unroll
      for(int off = 1; off < 16; off <<= 1) lv += __shfl_xor(lv, off, 64);
      l[mi][e] = lv;
    }
  #pragma unroll
  for(int mi = 0; mi < 2; mi++){
    #pragma unroll
    for(int e = 0; e < 4; e++){
      int row = rowbase + mi * 16 + lg * 4 + e;
      if(MODE == 0){
        float invl = 1.f / l[mi][e];
        int b = bh >> 3, h = bh & 7;
        #pragma unroll
        for(int ni2 = 0; ni2 < 4; ni2++){
          int col = ni2 * 16 + lr;
          size_t oi = ((size_t)b * 8192 + row) * 512 + h * 64 + col;
          o[oi] = f2b(pv[mi][ni2][e] * invl + b2f(o[oi]));
        }
      } else {
        #pragma unroll
        for(int ni2 = 0; ni2 < 4; ni2++){
          int col = ni2 * 16 + lr;
          pacc[(((size_t)blockIdx.z * 8192) + (size_t)bh * 256 + row) * 64 + col] = pv[mi][ni2][e];
        }
      }
    }
  }
  if(MODE == 1 && lr == 0){
    #pragma unroll
    for(int mi = 0; mi < 2; mi++)
      #pragma unroll
      for(int e = 0; e < 4; e++){
        int row = rowbase + mi * 16 + lg * 4 + e;
        plo[(size_t)blockIdx.z * 8192 + (size_t)bh * 256 + row] = l[mi][e];
      }
  }
}

// ------------- merge a3v split-K partials (16) -> av fp32 -------------
__global__ __launch_bounds__(64) void a3v_merge(const float* __restrict__ pacc,
                                                const float* __restrict__ plo,
                                                float* __restrict__ av){
  int row = blockIdx.x, d = threadIdx.x;
  float L = 0.f, acc = 0.f;
  #pragma unroll
  for(int p = 0; p < 16; p++){
    L += plo[(size_t)p * 8192 + row];
    acc += pacc[((size_t)p * 8192 + row) * 64 + d];
  }
  av[(size_t)row * 64 + d] = acc / L;
}

// ------------- W^T = (Z @ av)^T as bf16 (hi only); Z from triple -------------
__global__ __launch_bounds__(64) void zw_kernel(const u16* __restrict__ zh,
                                                const u16* __restrict__ zl,
                                                const u16* __restrict__ zl2,
                                                const float* __restrict__ av,
                                                u16* __restrict__ wth){
  int i = blockIdx.x & 255, bh = blockIdx.x >> 8, d = threadIdx.x;
  size_t zr = ((size_t)bh * 256 + i) * 256;
  const float* ab = av + (size_t)bh * 256 * 64;
  float s = 0.f;
  for(int j8 = 0; j8 < 32; j8++){
    u16x8 hv = *(const u16x8*)(zh + zr + j8 * 8);
    u16x8 lv = *(const u16x8*)(zl + zr + j8 * 8);
    u16x8 l2v = *(const u16x8*)(zl2 + zr + j8 * 8);
    #pragma unroll
    for(int e = 0; e < 8; e++){
      float zv = b2f(hv[e]) + b2f(lv[e]) + b2f(l2v[e]);
      s += zv * ab[(j8 * 8 + e) * 64 + d];
    }
  }
  wth[((size_t)bh * 64 + d) * 256 + i] = f2b(s);
}

// ------------- depthwise conv residual -> o (bf16 token layout), register-blocked -------------
__global__ __launch_bounds__(256) void conv_kernel(const u16* __restrict__ v,
                                                   const float* __restrict__ cw,
                                                   u16* __restrict__ o){
  __shared__ float wl[33];
  __shared__ float vt[64][104];
  int bh = blockIdx.y, b = bh >> 3, h = bh & 7;
  int r0 = blockIdx.x * 64;
  if(threadIdx.x < 33) wl[threadIdx.x] = cw[h * 33 + threadIdx.x];
  const u16* vb = v + (size_t)bh * 8192 * 64;
  for(int idx = threadIdx.x; idx < 768; idx += 256){
    int row = idx >> 3, c8 = (idx & 7) * 8;
    int gr = r0 - 16 + row;
    u16x8 u = {};
    if(gr >= 0 && gr < 8192) u = *(const u16x8*)(vb + (size_t)gr * 64 + c8);
    #pragma unroll
    for(int e = 0; e < 8; e++) vt[c8 + e][row] = b2f(u[e]);
  }
  __syncthreads();
  int d = threadIdx.x & 63, g = threadIdx.x >> 6;
  float vin[48];
  #pragma unroll
  for(int i = 0; i < 12; i++){
    f32x4 q4 = *(const f32x4*)&vt[d][g * 16 + i * 4];
    #pragma unroll
    for(int e = 0; e < 4; e++) vin[i * 4 + e] = q4[e];
  }
  float acc[16] = {};
  #pragma unroll
  for(int t = 0; t < 33; t++){
    float wt = wl[t];
    #pragma unroll
    for(int r = 0; r < 16; r++) acc[r] += wt * vin[r + t];
  }
  #pragma unroll
  for(int r = 0; r < 16; r++){
    size_t oi = ((size_t)b * 8192 + (r0 + g * 16 + r)) * 512 + h * 64 + d;
    o[oi] = f2b(acc[r]);
  }
}

extern "C" void kernel_launch(void* const* d_in, const int* in_sizes, int n_in,
                              void* d_out, int out_size, void* d_ws, size_t ws_size,
                              hipStream_t stream){
  (void)in_sizes; (void)n_in; (void)out_size; (void)ws_size;
  const float* x     = (const float*)d_in[0];
  const float* ln_w  = (const float*)d_in[1];
  const float* ln_b  = (const float*)d_in[2];
  const float* w_qkv = (const float*)d_in[3];
  const float* w_out = (const float*)d_in[4];
  const float* b_out = (const float*)d_in[5];
  const float* cw    = (const float*)d_in[6];
  float* out = (float*)d_out;

  char* base = (char*)d_ws;
  size_t off = 0;
  auto alloc = [&](size_t bytes)->void*{
    void* r = base + off; off += (bytes + 255) & ~(size_t)255; return r;
  };
  const size_t MSZ = 32ull * 65536 * 2;  // one bf16 matrix level: 4,194,304 B
  u16* xn      = (u16*)alloc(32768ull * 512 * 2);   // LN out; pinv: az+x2 triples; later pacc; later ob
  float2* stat = (float2*)alloc(32768ull * 8);
  u16* qb      = (u16*)alloc(32ull * 8192 * 64 * 2);
  u16* kb      = (u16*)alloc(32ull * 8192 * 64 * 2);
  u16* vb      = (u16*)alloc(32ull * 8192 * 64 * 2);
  u16* vtb     = (u16*)alloc(32ull * 8192 * 64 * 2);
  u16* wqkvT   = (u16*)alloc(1536ull * 512 * 2);
  u16* woutT   = (u16*)alloc(512ull * 512 * 2);
  // contiguous scratch region (dead during pinv) hosting x3 triple:
  float* wqkT  = (float*)alloc(1024ull * 512 * 4);
  float* xl    = (float*)alloc(1024ull * 512 * 4);
  float* qlf   = (float*)alloc(32ull * 256 * 64 * 4);
  float* klf   = (float*)alloc(32ull * 256 * 64 * 4);
  float* a2b   = (float*)alloc(32ull * 65536 * 4);
  // ---
  u16* qlh     = (u16*)alloc(32ull * 256 * 64 * 2);
  u16* qll     = (u16*)alloc(32ull * 256 * 64 * 2);
  u16* klh     = (u16*)alloc(32ull * 256 * 64 * 2);
  u16* kll     = (u16*)alloc(32ull * 256 * 64 * 2);
  u16* a2th    = (u16*)alloc(MSZ);
  u16* a2tl    = (u16*)alloc(MSZ);
  u16* a2tl2   = (u16*)alloc(MSZ);
  u16* zAh     = (u16*)alloc(MSZ);
  u16* zAl     = (u16*)alloc(MSZ);
  u16* zAl2    = (u16*)alloc(MSZ);
  u16* zBh     = (u16*)alloc(MSZ);
  u16* zBl     = (u16*)alloc(MSZ);
  u16* zBl2    = (u16*)alloc(MSZ);
  float* av    = (float*)alloc(32ull * 256 * 64 * 4);
  u16* wth     = (u16*)alloc(32ull * 64 * 256 * 2);
  u32* scal    = (u32*)alloc(256);
  u16* ob = xn;
  // aliases (live only during pinv loop):
  u16* azh  = xn;
  u16* azl  = (u16*)((char*)xn + MSZ);
  u16* azl2 = (u16*)((char*)xn + 2 * MSZ);
  u16* x2h  = (u16*)((char*)xn + 3 * MSZ);
  u16* x2l  = (u16*)((char*)xn + 4 * MSZ);
  u16* x2l2 = (u16*)((char*)xn + 5 * MSZ);
  u16* x3h  = (u16*)wqkT;
  u16* x3l  = (u16*)((char*)wqkT + MSZ);
  u16* x3l2 = (u16*)((char*)wqkT + 2 * MSZ);
  float* pacc = (float*)xn;
  float* plo  = (float*)wqkT;

  hipMemsetAsync(scal, 0, 8, stream);
  ln_kernel<<<32768, 256, 0, stream>>>(x, ln_w, ln_b, xn, stat);
  prep_weights<<<6144, 256, 0, stream>>>(w_qkv, w_out, wqkvT, woutT, wqkT);
  gemm128<0><<<dim3(256, 12), 256, 0, stream>>>(xn, wqkvT, qb, kb, vb, nullptr, nullptr, nullptr);
  vtrans_kernel<<<dim3(128, 32), 256, 0, stream>>>(vb, vtb);
  xl_kernel<<<1024, 256, 0, stream>>>(x, stat, ln_w, ln_b, xl);
  gemm_qlkl<<<dim3(16, 16), 256, 0, stream>>>(xl, wqkT, qlf, klf, qlh, qll, klh, kll);
  a2_kernel<<<dim3(256, 32), 256, 0, stream>>>(qlf, klf, a2b, a2th, a2tl, a2tl2);
  scale_kernel<<<32, 256, 0, stream>>>(a2b, scal);
  z0_kernel<<<dim3(4, 4, 32), 256, 0, stream>>>(a2b, zAh, zAl, zAl2, scal);

  u16* zPh = zAh; u16* zPl = zAl; u16* zPl2 = zAl2;
  u16* zQh = zBh; u16* zQl = zBl; u16* zQl2 = zBl2;
  for(int it = 0; it < 6; it++){
    gemm_pinv_mfma<<<dim3(16, 32), 256, 0, stream>>>(a2th, a2tl, a2tl2, zPh, zPl, zPl2,
                                                     azh, azl, azl2, 0.f, 0, 1.f);
    gemm_pinv_mfma<<<dim3(16, 32), 256, 0, stream>>>(azh, azl, azl2, azh, azl, azl2,
                                                     x2h, x2l, x2l2, 7.f, 1, 1.f);
    gemm_pinv_mfma<<<dim3(16, 32), 256, 0, stream>>>(azh, azl, azl2, x2h, x2l, x2l2,
                                                     x3h, x3l, x3l2, 11.f, 1, 1.f);
    gemm_pinv_mfma<<<dim3(16, 32), 256, 0, stream>>>(zPh, zPl, zPl2, x3h, x3l, x3l2,
                                                     zQh, zQl, zQl2, 13.f, 1, 0.25f);
    u16* t;
    t = zPh; zPh = zQh; zQh = t;
    t = zPl; zPl = zQl; zQl = t;
    t = zPl2; zPl2 = zQl2; zQl2 = t;
  }

  flash_kernel<1><<<dim3(2, 32, 16), 256, 36352, stream>>>(nullptr, qlh, qll, kb, nullptr, vtb,
                                                           nullptr, pacc, plo);
  a3v_merge<<<8192, 64, 0, stream>>>(pacc, plo, av);
  zw_kernel<<<8192, 64, 0, stream>>>(zPh, zPl, zPl2, av, wth);
  conv_kernel<<<dim3(128, 32), 256, 0, stream>>>(vb, cw, ob);
  flash_kernel<0><<<dim3(64, 32), 256, 45568, stream>>>(qb, nullptr, nullptr, klh, kll, wth,
                                                        ob, nullptr, nullptr);
  gemm128<1><<<dim3(256, 4), 256, 0, stream>>>(ob, woutT, nullptr, nullptr, nullptr, b_out, x, out);
}

// Round 15
// 906.801 us; speedup vs baseline: 1.0142x; 1.0142x over previous
//
#include <hip/hip_runtime.h>

#define DEV __device__ __forceinline__

typedef unsigned short u16;
typedef unsigned int   u32;
typedef u16   u16x4 __attribute__((ext_vector_type(4)));
typedef u16   u16x8 __attribute__((ext_vector_type(8)));
typedef __bf16 bf16x8 __attribute__((ext_vector_type(8)));
typedef float f32x4 __attribute__((ext_vector_type(4)));

DEV float b2f(u16 u){ return __uint_as_float(((u32)u) << 16); }
DEV u16 f2b(float f){ u32 u = __float_as_uint(f); u32 r = (u + 0x7fffu + ((u >> 16) & 1u)) >> 16; return (u16)r; }

// RNE triple split: x = h + l + l2 (each bf16), residual ~2^-27 rel
DEV void split3(float x, u16& h, u16& l, u16& l2){
  u32 ub = __float_as_uint(x);
  u32 rb = ub + 0x7fffu + ((ub >> 16) & 1u);
  float hf = __uint_as_float(rb & 0xffff0000u);
  float r1 = x - hf;
  u32 u1 = __float_as_uint(r1);
  u32 rb1 = u1 + 0x7fffu + ((u1 >> 16) & 1u);
  float lf = __uint_as_float(rb1 & 0xffff0000u);
  h = (u16)(rb >> 16);
  l = (u16)(rb1 >> 16);
  l2 = f2b(r1 - lf);
}

DEV f32x4 mfma16(u16x8 a, u16x8 b, f32x4 c){
  return __builtin_amdgcn_mfma_f32_16x16x32_bf16(
      __builtin_bit_cast(bf16x8, a), __builtin_bit_cast(bf16x8, b), c, 0, 0, 0);
}

// async global->LDS 16B (wave-uniform LDS base + lane*16; LDS must be linear)
DEV void gload16(const void* g, void* l){
  __builtin_amdgcn_global_load_lds(
      (const __attribute__((address_space(1))) u32*)g,
      (__attribute__((address_space(3))) u32*)l,
      16, 0, 0);
}

// ---------------- LayerNorm: x(f32) -> xn(bf16) + per-row stats ----------------
__global__ __launch_bounds__(256) void ln_kernel(const float* __restrict__ x,
                                                 const float* __restrict__ w,
                                                 const float* __restrict__ bb,
                                                 u16* __restrict__ xn,
                                                 float2* __restrict__ stats){
  int row = blockIdx.x;
  const float* xr = x + (size_t)row * 512;
  int t = threadIdx.x;
  float2 v = *(const float2*)(xr + t * 2);
  float s = v.x + v.y;
  float sq = v.x * v.x + v.y * v.y;
  #pragma unroll
  for(int off = 32; off; off >>= 1){ s += __shfl_xor(s, off, 64); sq += __shfl_xor(sq, off, 64); }
  __shared__ float rs[4], rq[4];
  int wv = t >> 6, ln = t & 63;
  if(ln == 0){ rs[wv] = s; rq[wv] = sq; }
  __syncthreads();
  s = rs[0] + rs[1] + rs[2] + rs[3];
  sq = rq[0] + rq[1] + rq[2] + rq[3];
  float mu = s * (1.f / 512.f);
  float var = sq * (1.f / 512.f) - mu * mu;
  float rstd = rsqrtf(var + 1e-5f);
  if(t == 0) stats[row] = make_float2(mu, rstd);
  float w0 = w[t * 2], w1 = w[t * 2 + 1], b0 = bb[t * 2], b1 = bb[t * 2 + 1];
  u16 u0 = f2b((v.x - mu) * rstd * w0 + b0);
  u16 u1 = f2b((v.y - mu) * rstd * w1 + b1);
  ((u32*)(xn + (size_t)row * 512))[t] = (u32)u0 | ((u32)u1 << 16);
}

// ------------- landmark means of LN(x) in fp32: xl[b*256+j][512] -------------
__global__ __launch_bounds__(256) void xl_kernel(const float* __restrict__ x,
                                                 const float2* __restrict__ stats,
                                                 const float* __restrict__ w,
                                                 const float* __restrict__ bb,
                                                 float* __restrict__ xl){
  int blk = blockIdx.x;          // b*256 + j
  int b = blk >> 8, j = blk & 255;
  int t = threadIdx.x;
  int d0 = t * 2;
  float acc0 = 0.f, acc1 = 0.f;
  size_t row0 = (size_t)b * 8192 + (size_t)j * 32;
  for(int tt = 0; tt < 32; tt++){
    size_t row = row0 + tt;
    float2 st = stats[row];
    const float* xr = x + row * 512;
    float2 v = *(const float2*)(xr + d0);
    acc0 += (v.x - st.x) * st.y;
    acc1 += (v.y - st.x) * st.y;
  }
  float* dst = xl + (size_t)blk * 512;
  dst[d0]     = acc0 * (1.f / 32.f) * w[d0]     + bb[d0];
  dst[d0 + 1] = acc1 * (1.f / 32.f) * w[d0 + 1] + bb[d0 + 1];
}

// ------------- fused weight prep: wqkvT(bf16), woutT(bf16), wqkT(f32) -------------
__global__ __launch_bounds__(256) void prep_weights(const float* __restrict__ w_qkv,
                                                    const float* __restrict__ w_out,
                                                    u16* __restrict__ wqkvT,
                                                    u16* __restrict__ woutT,
                                                    float* __restrict__ wqkT){
  int idx = blockIdx.x * 256 + threadIdx.x;
  if(idx < 786432){
    int k = idx / 1536, n = idx - k * 1536;
    wqkvT[(size_t)n * 512 + k] = f2b(w_qkv[idx]);
  } else if(idx < 786432 + 262144){
    int i2 = idx - 786432;
    int k = i2 >> 9, n = i2 & 511;
    woutT[(size_t)n * 512 + k] = f2b(w_out[i2]);
  } else {
    int i3 = idx - 786432 - 262144;
    int n = i3 >> 9, k = i3 & 511;
    wqkT[i3] = w_qkv[(size_t)k * 1536 + n];
  }
}

// ------------- v [key][d] -> vt [d][key] (bf16, per bh) -------------
__global__ __launch_bounds__(256) void vtrans_kernel(const u16* __restrict__ v,
                                                     u16* __restrict__ vt){
  __shared__ u16 tile[64][72];
  int bh = blockIdx.y, n0 = blockIdx.x * 64;
  int t = threadIdx.x;
  for(int s = t; s < 512; s += 256){
    int row = s >> 3, col = (s & 7) * 8;
    *(u16x8*)&tile[row][col] = *(const u16x8*)(v + ((size_t)bh * 8192 + n0 + row) * 64 + col);
  }
  __syncthreads();
  for(int s = t; s < 512; s += 256){
    int d = s >> 3, nc = (s & 7) * 8;
    u16x8 u;
    #pragma unroll
    for(int e = 0; e < 8; e++) u[e] = tile[nc + e][d];
    *(u16x8*)(vt + ((size_t)bh * 64 + d) * 8192 + n0 + nc) = u;
  }
}

// ------------- big bf16 GEMM: A[M x 512] @ BT[N x 512]^T, 128x128 tile -------------
template<int EPI>
__global__ __launch_bounds__(256) void gemm128(const u16* __restrict__ A,
                                               const u16* __restrict__ BT,
                                               u16* __restrict__ qo, u16* __restrict__ ko, u16* __restrict__ vo,
                                               const float* __restrict__ bout,
                                               const float* __restrict__ xres,
                                               float* __restrict__ dout){
  __shared__ u16 As[128 * 32];
  __shared__ u16 Bs[128 * 32];
  const int K = 512;
  int nby = gridDim.y;
  int nwg = gridDim.x * nby;
  int orig = blockIdx.y * gridDim.x + blockIdx.x;
  int cpx = nwg >> 3;
  int wg = (orig & 7) * cpx + (orig >> 3);
  int fx = wg / nby, fy = wg - fx * nby;
  int tb_m = fx * 128, tb_n = fy * 128;
  int tid = threadIdx.x, lane = tid & 63, w = tid >> 6;
  int wm = (w >> 1) * 64, wn = (w & 1) * 64;
  f32x4 acc[4][4] = {};
  int srow = tid >> 2, sk = (tid & 3) * 8;
  const u16* Ag = A + (size_t)(tb_m + srow) * K + sk;
  const u16* Bg = BT + (size_t)(tb_n + srow) * K + sk;
  u16* Al = As + tid * 8;
  u16* Bl = Bs + tid * 8;
  for(int kk = 0; kk < K; kk += 32){
    __syncthreads();
    gload16(Ag + kk, Al);
    gload16(Ag + kk + (size_t)64 * K, Al + 2048);
    gload16(Bg + kk, Bl);
    gload16(Bg + kk + (size_t)64 * K, Bl + 2048);
    __syncthreads();
    int r = lane & 15, ko2 = (lane >> 4) * 8;
    u16x8 af[4], bf[4];
    #pragma unroll
    for(int mi = 0; mi < 4; mi++) af[mi] = *(const u16x8*)&As[(wm + mi * 16 + r) * 32 + ko2];
    #pragma unroll
    for(int ni = 0; ni < 4; ni++) bf[ni] = *(const u16x8*)&Bs[(wn + ni * 16 + r) * 32 + ko2];
    #pragma unroll
    for(int mi = 0; mi < 4; mi++)
      #pragma unroll
      for(int ni = 0; ni < 4; ni++)
        acc[mi][ni] = mfma16(af[mi], bf[ni], acc[mi][ni]);
  }
  int r = lane & 15, rr = (lane >> 4) * 4;
  #pragma unroll
  for(int mi = 0; mi < 4; mi++)
    #pragma unroll
    for(int ni = 0; ni < 4; ni++){
      int col = tb_n + wn + ni * 16 + r;
      #pragma unroll
      for(int e = 0; e < 4; e++){
        int row = tb_m + wm + mi * 16 + rr + e;
        float val = acc[mi][ni][e];
        if(EPI == 0){
          int t3 = col >> 9, h = (col >> 6) & 7, dh = col & 63;
          int b = row >> 13, n = row & 8191;
          if(t3 == 0) val *= 0.125f;
          u16* dst = (t3 == 0 ? qo : (t3 == 1 ? ko : vo));
          dst[(((size_t)(b * 8 + h) * 8192) + n) * 64 + dh] = f2b(val);
        } else {
          val += bout[col] + xres[(size_t)row * 512 + col];
          dout[(size_t)row * 512 + col] = val;
        }
      }
    }
}

// ------------- fp32 GEMM: ql/kl = xl @ wqkT^T, scatter epi + hi/lo split -------------
__global__ __launch_bounds__(256) void gemm_qlkl(const float* __restrict__ A,
                                                 const float* __restrict__ BT,
                                                 float* __restrict__ qlf,
                                                 float* __restrict__ klf,
                                                 u16* __restrict__ qlh, u16* __restrict__ qll,
                                                 u16* __restrict__ klh, u16* __restrict__ kll){
  __shared__ float As[64][17];
  __shared__ float Bs[64][17];
  int tb_m = blockIdx.x * 64, tb_n = blockIdx.y * 64;
  int tid = threadIdx.x;
  int ty = tid >> 4, tx = tid & 15;
  float acc[4][4] = {};
  int srow = tid >> 2, sseg = (tid & 3) * 4;
  const float* Ag = A + (size_t)(tb_m + srow) * 512 + sseg;
  const float* Bg = BT + (size_t)(tb_n + srow) * 512 + sseg;
  for(int kk = 0; kk < 512; kk += 16){
    __syncthreads();
    f32x4 a4 = *(const f32x4*)(Ag + kk);
    f32x4 b4 = *(const f32x4*)(Bg + kk);
    #pragma unroll
    for(int e = 0; e < 4; e++){ As[srow][sseg + e] = a4[e]; Bs[srow][sseg + e] = b4[e]; }
    __syncthreads();
    #pragma unroll
    for(int k2 = 0; k2 < 16; k2++){
      float a[4], b[4];
      #pragma unroll
      for(int i = 0; i < 4; i++) a[i] = As[ty * 4 + i][k2];
      #pragma unroll
      for(int jv = 0; jv < 4; jv++) b[jv] = Bs[tx * 4 + jv][k2];
      #pragma unroll
      for(int i = 0; i < 4; i++)
        #pragma unroll
        for(int jv = 0; jv < 4; jv++) acc[i][jv] += a[i] * b[jv];
    }
  }
  #pragma unroll
  for(int i = 0; i < 4; i++)
    #pragma unroll
    for(int jv = 0; jv < 4; jv++){
      int r = tb_m + ty * 4 + i;
      int c = tb_n + tx * 4 + jv;
      int b = r >> 8, jl = r & 255;
      float val = acc[i][jv];
      if(c < 512){
        float q = val * 0.125f;
        size_t qi = (((size_t)(b * 8 + (c >> 6)) * 256) + jl) * 64 + (c & 63);
        qlf[qi] = q;
        u16 hi = f2b(q);
        qlh[qi] = hi; qll[qi] = f2b(q - b2f(hi));
      } else {
        int c2 = c - 512;
        size_t ki = (((size_t)(b * 8 + (c2 >> 6)) * 256) + jl) * 64 + (c2 & 63);
        klf[ki] = val;
        u16 hi = f2b(val);
        klh[ki] = hi; kll[ki] = f2b(val - b2f(hi));
      }
    }
}

// ------------- batched pinv GEMM via bf16 triple-split MFMA -------------
__global__ __launch_bounds__(256) void gemm_pinv_mfma(
    const u16* __restrict__ Ah, const u16* __restrict__ Al, const u16* __restrict__ Al2,
    const u16* __restrict__ Bh, const u16* __restrict__ Bl, const u16* __restrict__ Bl2,
    u16* __restrict__ Ch, u16* __restrict__ Cl, u16* __restrict__ Cl2,
    float dB, int bneg, float osc){
  __shared__ u16 As_[3][64][40];   // [level][row][k]
  __shared__ u16 Bs_[3][64][40];   // [level][col][k]  (transposed tile)
  int bh = blockIdx.y;
  size_t base = (size_t)bh * 65536;
  int tb_m = (blockIdx.x >> 2) * 64, tb_n = (blockIdx.x & 3) * 64;
  int tid = threadIdx.x, lane = tid & 63, w = tid >> 6;
  int lr = lane & 15, lg = lane >> 4;
  int wm = (w >> 1) * 32, wn = (w & 1) * 32;
  f32x4 acc[2][2] = {};
  int arow = tid >> 2, akq = (tid & 3) * 8;
  int bcol = tid & 63, bkq = tid >> 6;
  u16 sx = bneg ? (u16)0x8000u : (u16)0;
  size_t aoff = base + (size_t)(tb_m + arow) * 256 + akq;
  size_t boff = base + (size_t)(tb_n + bcol);
  for(int kk = 0; kk < 256; kk += 32){
    u16x8 ra0 = *(const u16x8*)(Ah + aoff + kk);
    u16x8 ra1 = *(const u16x8*)(Al + aoff + kk);
    u16x8 ra2 = *(const u16x8*)(Al2 + aoff + kk);
    u16x8 rb0, rb1, rb2;
    #pragma unroll
    for(int j = 0; j < 8; j++){
      size_t bi = boff + (size_t)(kk + bkq * 8 + j) * 256;
      rb0[j] = Bh[bi] ^ sx;
      rb1[j] = Bl[bi] ^ sx;
      rb2[j] = Bl2[bi] ^ sx;
    }
    __syncthreads();
    *(u16x8*)&As_[0][arow][akq] = ra0;
    *(u16x8*)&As_[1][arow][akq] = ra1;
    *(u16x8*)&As_[2][arow][akq] = ra2;
    *(u16x8*)&Bs_[0][bcol][bkq * 8] = rb0;
    *(u16x8*)&Bs_[1][bcol][bkq * 8] = rb1;
    *(u16x8*)&Bs_[2][bcol][bkq * 8] = rb2;
    __syncthreads();
    u16x8 af[3][2], bf[3][2];
    #pragma unroll
    for(int v = 0; v < 3; v++)
      #pragma unroll
      for(int mi = 0; mi < 2; mi++){
        af[v][mi] = *(const u16x8*)&As_[v][wm + mi * 16 + lr][lg * 8];
        bf[v][mi] = *(const u16x8*)&Bs_[v][wn + mi * 16 + lr][lg * 8];
      }
    #pragma unroll
    for(int mi = 0; mi < 2; mi++)
      #pragma unroll
      for(int ni = 0; ni < 2; ni++){
        acc[mi][ni] = mfma16(af[1][mi], bf[1][ni], acc[mi][ni]);   // l*l
        acc[mi][ni] = mfma16(af[2][mi], bf[0][ni], acc[mi][ni]);   // l2*h
        acc[mi][ni] = mfma16(af[0][mi], bf[2][ni], acc[mi][ni]);   // h*l2
        acc[mi][ni] = mfma16(af[1][mi], bf[0][ni], acc[mi][ni]);   // l*h
        acc[mi][ni] = mfma16(af[0][mi], bf[1][ni], acc[mi][ni]);   // h*l
        acc[mi][ni] = mfma16(af[0][mi], bf[0][ni], acc[mi][ni]);   // h*h
      }
  }
  #pragma unroll
  for(int mi = 0; mi < 2; mi++)
    #pragma unroll
    for(int ni = 0; ni < 2; ni++)
      #pragma unroll
      for(int e = 0; e < 4; e++){
        int r = tb_m + wm + mi * 16 + lg * 4 + e;
        int c = tb_n + wn + ni * 16 + lr;
        size_t idx = base + (size_t)r * 256 + c;
        float arec = b2f(Ah[idx]) + b2f(Al[idx]) + b2f(Al2[idx]);
        float val = osc * (dB * arec + acc[mi][ni][e]);
        u16 h, l, l2;
        split3(val, h, l, l2);
        Ch[idx] = h; Cl[idx] = l; Cl2[idx] = l2;
      }
}

// ------------- a2 = softmax(q_l @ k_l^T) per row, fp32 + triple -------------
__global__ __launch_bounds__(256) void a2_kernel(const float* __restrict__ qlf,
                                                 const float* __restrict__ klf,
                                                 float* __restrict__ a2,
                                                 u16* __restrict__ a2h, u16* __restrict__ a2l,
                                                 u16* __restrict__ a2l2){
  int i = blockIdx.x, bh = blockIdx.y, j = threadIdx.x;
  const float* qp = qlf + ((size_t)bh * 256 + i) * 64;
  const float* kp = klf + ((size_t)bh * 256 + j) * 64;
  float s = 0.f;
  #pragma unroll
  for(int d0 = 0; d0 < 16; d0++){
    f32x4 uq = *(const f32x4*)(qp + d0 * 4);
    f32x4 uk = *(const f32x4*)(kp + d0 * 4);
    #pragma unroll
    for(int e = 0; e < 4; e++) s += uq[e] * uk[e];
  }
  __shared__ float red[256];
  red[j] = s; __syncthreads();
  for(int off = 128; off; off >>= 1){ if(j < off) red[j] = fmaxf(red[j], red[j + off]); __syncthreads(); }
  float m = red[0]; __syncthreads();
  float p = expf(s - m);
  red[j] = p; __syncthreads();
  for(int off = 128; off; off >>= 1){ if(j < off) red[j] += red[j + off]; __syncthreads(); }
  float denom = red[0];
  float vv = p / denom;
  size_t idx = ((size_t)bh * 256 + i) * 256 + j;
  a2[idx] = vv;
  u16 h, l, l2;
  split3(vv, h, l, l2);
  a2h[idx] = h; a2l[idx] = l; a2l2[idx] = l2;
}

// ------------- scale maxes -------------
__global__ __launch_bounds__(256) void scale_kernel(const float* __restrict__ a2, u32* __restrict__ maxes){
  int bh = blockIdx.x, t = threadIdx.x;
  const float* p = a2 + (size_t)bh * 65536;
  float cs = 0.f, rs = 0.f;
  for(int i = 0; i < 256; i++) cs += p[i * 256 + t];
  for(int j = 0; j < 256; j++) rs += p[t * 256 + j];
  __shared__ float rc[256], rr[256];
  rc[t] = cs; rr[t] = rs; __syncthreads();
  for(int off = 128; off; off >>= 1){
    if(t < off){ rc[t] = fmaxf(rc[t], rc[t + off]); rr[t] = fmaxf(rr[t], rr[t + off]); }
    __syncthreads();
  }
  if(t == 0){
    atomicMax(&maxes[0], __float_as_uint(rc[0]));
    atomicMax(&maxes[1], __float_as_uint(rr[0]));
  }
}

// ------------- z0 = a2^T / scale -> triple (tiled transpose) -------------
__global__ __launch_bounds__(256) void z0_kernel(const float* __restrict__ a2,
                                                 u16* __restrict__ zh, u16* __restrict__ zl,
                                                 u16* __restrict__ zl2,
                                                 const u32* __restrict__ maxes){
  __shared__ float tile[64][65];
  float inv = 1.f / (__uint_as_float(maxes[0]) * __uint_as_float(maxes[1]));
  int bh = blockIdx.z;
  int i0 = blockIdx.x * 64, j0 = blockIdx.y * 64;
  const float* src = a2 + (size_t)bh * 65536;
  size_t dbase = (size_t)bh * 65536;
  for(int s = threadIdx.x; s < 1024; s += 256){
    int r = s >> 4, c4 = (s & 15) * 4;
    f32x4 v = *(const f32x4*)(src + (size_t)(i0 + r) * 256 + j0 + c4);
    #pragma unroll
    for(int e = 0; e < 4; e++) tile[r][c4 + e] = v[e];
  }
  __syncthreads();
  for(int s = threadIdx.x; s < 1024; s += 256){
    int jr = s >> 4, c4 = (s & 15) * 4;
    u16x4 hv, lv, l2v;
    #pragma unroll
    for(int e = 0; e < 4; e++){
      float val = tile[c4 + e][jr] * inv;
      u16 h, l, l2;
      split3(val, h, l, l2);
      hv[e] = h; lv[e] = l; l2v[e] = l2;
    }
    size_t doff = dbase + (size_t)(j0 + jr) * 256 + i0 + c4;
    *(u16x4*)(zh + doff) = hv;
    *(u16x4*)(zl + doff) = lv;
    *(u16x4*)(zl2 + doff) = l2v;
  }
}

// ------------- unified MFMA flash attention, LDS-staged K/V, single-chain PV -------------
// MODE 0 (a1): A=qb exact; B=kl hi/lo; V=W hi only; 256 keys; RMW into o.  smem 45568 B
// MODE 1 (a3v): A=ql hi/lo; B=kb exact; V=v^T exact; 512-key split.        smem 36352 B
template<int MODE>
__global__ __launch_bounds__(256) void flash_kernel(
    const u16* __restrict__ Aex,
    const u16* __restrict__ Ah_, const u16* __restrict__ Al_,
    const u16* __restrict__ Bh_, const u16* __restrict__ Bl_,
    const u16* __restrict__ Vh_,
    u16* __restrict__ o,
    float* __restrict__ pacc, float* __restrict__ plo){
  extern __shared__ char smem[];
  u32 (*pbuf)[32][35] = (u32(*)[32][35])smem;                  // 17920 B; stores P-hi (low16)
  u16 (*ksh)[72] = (u16(*)[72])(smem + 17920);                 // [64][72] key-major
  u16 (*vsh)[72] = (u16(*)[72])(smem + 17920 + 9216);          // [64][72] d-major
  u16 (*ksl)[72] = (u16(*)[72])(smem + 17920 + 2 * 9216);      // MODE0 only

  int tid = threadIdx.x;
  int w = tid >> 6, lane = tid & 63;
  int lr = lane & 15, lg = lane >> 4;
  int bh = blockIdx.y;
  int rowbase = blockIdx.x * 128 + w * 32;
  constexpr int NT = (MODE == 0) ? 4 : 8;
  int kbase = (MODE == 0) ? 0 : blockIdx.z * 512;
  int srow = tid >> 2, sseg = (tid & 3) * 16;

  u16x8 afh[2][2], afl[2][2];
  #pragma unroll
  for(int mi = 0; mi < 2; mi++)
    #pragma unroll
    for(int ks = 0; ks < 2; ks++){
      int r = rowbase + mi * 16 + lr;
      if(MODE == 0){
        afh[mi][ks] = *(const u16x8*)(Aex + ((size_t)bh * 8192 + r) * 64 + ks * 32 + lg * 8);
      } else {
        size_t idx = ((size_t)bh * 256 + r) * 64 + ks * 32 + lg * 8;
        afh[mi][ks] = *(const u16x8*)(Ah_ + idx);
        afl[mi][ks] = *(const u16x8*)(Al_ + idx);
      }
    }

  f32x4 pv[2][4] = {};
  float l[2][4] = {};

  for(int t = 0; t < NT; t++){
    int koff = t * 64;
    __syncthreads();
    if(MODE == 0){
      size_t kix = ((size_t)bh * 256 + koff + srow) * 64 + sseg;
      *(u16x8*)&ksh[srow][sseg]     = *(const u16x8*)(Bh_ + kix);
      *(u16x8*)&ksh[srow][sseg + 8] = *(const u16x8*)(Bh_ + kix + 8);
      *(u16x8*)&ksl[srow][sseg]     = *(const u16x8*)(Bl_ + kix);
      *(u16x8*)&ksl[srow][sseg + 8] = *(const u16x8*)(Bl_ + kix + 8);
      size_t vix = ((size_t)bh * 64 + srow) * 256 + koff + sseg;
      *(u16x8*)&vsh[srow][sseg]     = *(const u16x8*)(Vh_ + vix);
      *(u16x8*)&vsh[srow][sseg + 8] = *(const u16x8*)(Vh_ + vix + 8);
    } else {
      size_t kix = ((size_t)bh * 8192 + kbase + koff + srow) * 64 + sseg;
      *(u16x8*)&ksh[srow][sseg]     = *(const u16x8*)(Bh_ + kix);
      *(u16x8*)&ksh[srow][sseg + 8] = *(const u16x8*)(Bh_ + kix + 8);
      size_t vix = ((size_t)bh * 64 + srow) * 8192 + kbase + koff + sseg;
      *(u16x8*)&vsh[srow][sseg]     = *(const u16x8*)(Vh_ + vix);
      *(u16x8*)&vsh[srow][sseg + 8] = *(const u16x8*)(Vh_ + vix + 8);
    }
    __syncthreads();
    #pragma unroll
    for(int half = 0; half < 2; half++){
      u16x8 bfh[2][2], bfl[2][2];
      #pragma unroll
      for(int ni = 0; ni < 2; ni++){
        int krow = half * 32 + ni * 16 + lr;
        #pragma unroll
        for(int ks = 0; ks < 2; ks++){
          bfh[ni][ks] = *(const u16x8*)&ksh[krow][ks * 32 + lg * 8];
          if(MODE == 0) bfl[ni][ks] = *(const u16x8*)&ksl[krow][ks * 32 + lg * 8];
        }
      }
      f32x4 sv[2][2];
      #pragma unroll
      for(int mi = 0; mi < 2; mi++)
        #pragma unroll
        for(int ni = 0; ni < 2; ni++) sv[mi][ni] = (f32x4){0.f, 0.f, 0.f, 0.f};
      __builtin_amdgcn_s_setprio(1);
      #pragma unroll
      for(int ks = 0; ks < 2; ks++)
        #pragma unroll
        for(int mi = 0; mi < 2; mi++)
          #pragma unroll
          for(int ni = 0; ni < 2; ni++){
            sv[mi][ni] = mfma16(afh[mi][ks], bfh[ni][ks], sv[mi][ni]);
            if(MODE == 0) sv[mi][ni] = mfma16(afh[mi][ks], bfl[ni][ks], sv[mi][ni]);
            else          sv[mi][ni] = mfma16(afl[mi][ks], bfh[ni][ks], sv[mi][ni]);
          }
      __builtin_amdgcn_s_setprio(0);
      // exp + per-lane l; store P-hi into pbuf (transpose)
      #pragma unroll
      for(int mi = 0; mi < 2; mi++)
        #pragma unroll
        for(int ni = 0; ni < 2; ni++)
          #pragma unroll
          for(int e = 0; e < 4; e++){
            float p = __expf(sv[mi][ni][e]);
            l[mi][e] += p;
            u32 pb = __float_as_uint(p);
            u32 rb = pb + 0x7fffu + ((pb >> 16) & 1u);
            pbuf[w][mi * 16 + lg * 4 + e][ni * 16 + lr] = rb >> 16;
          }
      u16x8 pah[2];
      #pragma unroll
      for(int mi = 0; mi < 2; mi++){
        u32 tv[8];
        #pragma unroll
        for(int e2 = 0; e2 < 8; e2++) tv[e2] = pbuf[w][mi * 16 + lr][lg * 8 + e2];
        u32* ph = (u32*)&pah[mi];
        #pragma unroll
        for(int q = 0; q < 4; q++)
          ph[q] = __builtin_amdgcn_perm(tv[2 * q + 1], tv[2 * q], 0x05040100u);
      }
      __builtin_amdgcn_s_setprio(1);
      #pragma unroll
      for(int ni2 = 0; ni2 < 4; ni2++){
        int d = ni2 * 16 + lr;
        u16x8 vh = *(const u16x8*)&vsh[d][half * 32 + lg * 8];
        #pragma unroll
        for(int mi = 0; mi < 2; mi++)
          pv[mi][ni2] = mfma16(pah[mi], vh, pv[mi][ni2]);
      }
      __builtin_amdgcn_s_setprio(0);
    }
  }
  #pragma unroll
  for(int mi = 0; mi < 2; mi++)
    #pragma unroll
    for(int e = 0; e < 4; e++){
      float lv = l[mi][e];
      #pragma unroll
      for(int off = 1; off < 16; off <<= 1) lv += __shfl_xor(lv, off, 64);
      l[mi][e] = lv;
    }
  #pragma unroll
  for(int mi = 0; mi < 2; mi++){
    #pragma unroll
    for(int e = 0; e < 4; e++){
      int row = rowbase + mi * 16 + lg * 4 + e;
      if(MODE == 0){
        float invl = 1.f / l[mi][e];
        int b = bh >> 3, h = bh & 7;
        #pragma unroll
        for(int ni2 = 0; ni2 < 4; ni2++){
          int col = ni2 * 16 + lr;
          size_t oi = ((size_t)b * 8192 + row) * 512 + h * 64 + col;
          o[oi] = f2b(pv[mi][ni2][e] * invl + b2f(o[oi]));
        }
      } else {
        #pragma unroll
        for(int ni2 = 0; ni2 < 4; ni2++){
          int col = ni2 * 16 + lr;
          pacc[(((size_t)blockIdx.z * 8192) + (size_t)bh * 256 + row) * 64 + col] = pv[mi][ni2][e];
        }
      }
    }
  }
  if(MODE == 1 && lr == 0){
    #pragma unroll
    for(int mi = 0; mi < 2; mi++)
      #pragma unroll
      for(int e = 0; e < 4; e++){
        int row = rowbase + mi * 16 + lg * 4 + e;
        plo[(size_t)blockIdx.z * 8192 + (size_t)bh * 256 + row] = l[mi][e];
      }
  }
}

// ------------- merge a3v split-K partials (16) -> av fp32 -------------
__global__ __launch_bounds__(64) void a3v_merge(const float* __restrict__ pacc,
                                                const float* __restrict__ plo,
                                                float* __restrict__ av){
  int row = blockIdx.x, d = threadIdx.x;
  float L = 0.f, acc = 0.f;
  #pragma unroll
  for(int p = 0; p < 16; p++){
    L += plo[(size_t)p * 8192 + row];
    acc += pacc[((size_t)p * 8192 + row) * 64 + d];
  }
  av[(size_t)row * 64 + d] = acc / L;
}

// ------------- W^T = (Z @ av)^T as bf16 (hi only); Z from triple -------------
__global__ __launch_bounds__(64) void zw_kernel(const u16* __restrict__ zh,
                                                const u16* __restrict__ zl,
                                                const u16* __restrict__ zl2,
                                                const float* __restrict__ av,
                                                u16* __restrict__ wth){
  int i = blockIdx.x & 255, bh = blockIdx.x >> 8, d = threadIdx.x;
  size_t zr = ((size_t)bh * 256 + i) * 256;
  const float* ab = av + (size_t)bh * 256 * 64;
  float s = 0.f;
  for(int j8 = 0; j8 < 32; j8++){
    u16x8 hv = *(const u16x8*)(zh + zr + j8 * 8);
    u16x8 lv = *(const u16x8*)(zl + zr + j8 * 8);
    u16x8 l2v = *(const u16x8*)(zl2 + zr + j8 * 8);
    #pragma unroll
    for(int e = 0; e < 8; e++){
      float zv = b2f(hv[e]) + b2f(lv[e]) + b2f(l2v[e]);
      s += zv * ab[(j8 * 8 + e) * 64 + d];
    }
  }
  wth[((size_t)bh * 64 + d) * 256 + i] = f2b(s);
}

// ------------- depthwise conv residual -> o (bf16 token layout), register-blocked -------------
__global__ __launch_bounds__(256) void conv_kernel(const u16* __restrict__ v,
                                                   const float* __restrict__ cw,
                                                   u16* __restrict__ o){
  __shared__ float wl[33];
  __shared__ float vt[64][104];
  int bh = blockIdx.y, b = bh >> 3, h = bh & 7;
  int r0 = blockIdx.x * 64;
  if(threadIdx.x < 33) wl[threadIdx.x] = cw[h * 33 + threadIdx.x];
  const u16* vb = v + (size_t)bh * 8192 * 64;
  for(int idx = threadIdx.x; idx < 768; idx += 256){
    int row = idx >> 3, c8 = (idx & 7) * 8;
    int gr = r0 - 16 + row;
    u16x8 u = {};
    if(gr >= 0 && gr < 8192) u = *(const u16x8*)(vb + (size_t)gr * 64 + c8);
    #pragma unroll
    for(int e = 0; e < 8; e++) vt[c8 + e][row] = b2f(u[e]);
  }
  __syncthreads();
  int d = threadIdx.x & 63, g = threadIdx.x >> 6;
  float vin[48];
  #pragma unroll
  for(int i = 0; i < 12; i++){
    f32x4 q4 = *(const f32x4*)&vt[d][g * 16 + i * 4];
    #pragma unroll
    for(int e = 0; e < 4; e++) vin[i * 4 + e] = q4[e];
  }
  float acc[16] = {};
  #pragma unroll
  for(int t = 0; t < 33; t++){
    float wt = wl[t];
    #pragma unroll
    for(int r = 0; r < 16; r++) acc[r] += wt * vin[r + t];
  }
  #pragma unroll
  for(int r = 0; r < 16; r++){
    size_t oi = ((size_t)b * 8192 + (r0 + g * 16 + r)) * 512 + h * 64 + d;
    o[oi] = f2b(acc[r]);
  }
}

extern "C" void kernel_launch(void* const* d_in, const int* in_sizes, int n_in,
                              void* d_out, int out_size, void* d_ws, size_t ws_size,
                              hipStream_t stream){
  (void)in_sizes; (void)n_in; (void)out_size; (void)ws_size;
  const float* x     = (const float*)d_in[0];
  const float* ln_w  = (const float*)d_in[1];
  const float* ln_b  = (const float*)d_in[2];
  const float* w_qkv = (const float*)d_in[3];
  const float* w_out = (const float*)d_in[4];
  const float* b_out = (const float*)d_in[5];
  const float* cw    = (const float*)d_in[6];
  float* out = (float*)d_out;

  char* base = (char*)d_ws;
  size_t off = 0;
  auto alloc = [&](size_t bytes)->void*{
    void* r = base + off; off += (bytes + 255) & ~(size_t)255; return r;
  };
  const size_t MSZ = 32ull * 65536 * 2;  // one bf16 matrix level: 4,194,304 B
  u16* xn      = (u16*)alloc(32768ull * 512 * 2);   // LN out; pinv: az+x2 triples; later pacc; later ob
  float2* stat = (float2*)alloc(32768ull * 8);
  u16* qb      = (u16*)alloc(32ull * 8192 * 64 * 2);
  u16* kb      = (u16*)alloc(32ull * 8192 * 64 * 2);
  u16* vb      = (u16*)alloc(32ull * 8192 * 64 * 2);
  u16* vtb     = (u16*)alloc(32ull * 8192 * 64 * 2);
  u16* wqkvT   = (u16*)alloc(1536ull * 512 * 2);
  u16* woutT   = (u16*)alloc(512ull * 512 * 2);
  // contiguous scratch region (dead during pinv) hosting x3 triple:
  float* wqkT  = (float*)alloc(1024ull * 512 * 4);
  float* xl    = (float*)alloc(1024ull * 512 * 4);
  float* qlf   = (float*)alloc(32ull * 256 * 64 * 4);
  float* klf   = (float*)alloc(32ull * 256 * 64 * 4);
  float* a2b   = (float*)alloc(32ull * 65536 * 4);
  // ---
  u16* qlh     = (u16*)alloc(32ull * 256 * 64 * 2);
  u16* qll     = (u16*)alloc(32ull * 256 * 64 * 2);
  u16* klh     = (u16*)alloc(32ull * 256 * 64 * 2);
  u16* kll     = (u16*)alloc(32ull * 256 * 64 * 2);
  u16* a2th    = (u16*)alloc(MSZ);
  u16* a2tl    = (u16*)alloc(MSZ);
  u16* a2tl2   = (u16*)alloc(MSZ);
  u16* zAh     = (u16*)alloc(MSZ);
  u16* zAl     = (u16*)alloc(MSZ);
  u16* zAl2    = (u16*)alloc(MSZ);
  u16* zBh     = (u16*)alloc(MSZ);
  u16* zBl     = (u16*)alloc(MSZ);
  u16* zBl2    = (u16*)alloc(MSZ);
  float* av    = (float*)alloc(32ull * 256 * 64 * 4);
  u16* wth     = (u16*)alloc(32ull * 64 * 256 * 2);
  u32* scal    = (u32*)alloc(256);
  u16* ob = xn;
  // aliases (live only during pinv loop):
  u16* azh  = xn;
  u16* azl  = (u16*)((char*)xn + MSZ);
  u16* azl2 = (u16*)((char*)xn + 2 * MSZ);
  u16* x2h  = (u16*)((char*)xn + 3 * MSZ);
  u16* x2l  = (u16*)((char*)xn + 4 * MSZ);
  u16* x2l2 = (u16*)((char*)xn + 5 * MSZ);
  u16* x3h  = (u16*)wqkT;
  u16* x3l  = (u16*)((char*)wqkT + MSZ);
  u16* x3l2 = (u16*)((char*)wqkT + 2 * MSZ);
  float* pacc = (float*)xn;
  float* plo  = (float*)wqkT;

  hipMemsetAsync(scal, 0, 8, stream);
  ln_kernel<<<32768, 256, 0, stream>>>(x, ln_w, ln_b, xn, stat);
  prep_weights<<<6144, 256, 0, stream>>>(w_qkv, w_out, wqkvT, woutT, wqkT);
  gemm128<0><<<dim3(256, 12), 256, 0, stream>>>(xn, wqkvT, qb, kb, vb, nullptr, nullptr, nullptr);
  vtrans_kernel<<<dim3(128, 32), 256, 0, stream>>>(vb, vtb);
  xl_kernel<<<1024, 256, 0, stream>>>(x, stat, ln_w, ln_b, xl);
  gemm_qlkl<<<dim3(16, 16), 256, 0, stream>>>(xl, wqkT, qlf, klf, qlh, qll, klh, kll);
  a2_kernel<<<dim3(256, 32), 256, 0, stream>>>(qlf, klf, a2b, a2th, a2tl, a2tl2);
  scale_kernel<<<32, 256, 0, stream>>>(a2b, scal);
  z0_kernel<<<dim3(4, 4, 32), 256, 0, stream>>>(a2b, zAh, zAl, zAl2, scal);

  u16* zPh = zAh; u16* zPl = zAl; u16* zPl2 = zAl2;
  u16* zQh = zBh; u16* zQl = zBl; u16* zQl2 = zBl2;
  for(int it = 0; it < 6; it++){
    gemm_pinv_mfma<<<dim3(16, 32), 256, 0, stream>>>(a2th, a2tl, a2tl2, zPh, zPl, zPl2,
                                                     azh, azl, azl2, 0.f, 0, 1.f);
    gemm_pinv_mfma<<<dim3(16, 32), 256, 0, stream>>>(azh, azl, azl2, azh, azl, azl2,
                                                     x2h, x2l, x2l2, 7.f, 1, 1.f);
    gemm_pinv_mfma<<<dim3(16, 32), 256, 0, stream>>>(azh, azl, azl2, x2h, x2l, x2l2,
                                                     x3h, x3l, x3l2, 11.f, 1, 1.f);
    gemm_pinv_mfma<<<dim3(16, 32), 256, 0, stream>>>(zPh, zPl, zPl2, x3h, x3l, x3l2,
                                                     zQh, zQl, zQl2, 13.f, 1, 0.25f);
    u16* t;
    t = zPh; zPh = zQh; zQh = t;
    t = zPl; zPl = zQl; zQl = t;
    t = zPl2; zPl2 = zQl2; zQl2 = t;
  }

  flash_kernel<1><<<dim3(2, 32, 16), 256, 36352, stream>>>(nullptr, qlh, qll, kb, nullptr, vtb,
                                                           nullptr, pacc, plo);
  a3v_merge<<<8192, 64, 0, stream>>>(pacc, plo, av);
  zw_kernel<<<8192, 64, 0, stream>>>(zPh, zPl, zPl2, av, wth);
  conv_kernel<<<dim3(128, 32), 256, 0, stream>>>(vb, cw, ob);
  flash_kernel<0><<<dim3(64, 32), 256, 45568, stream>>>(qb, nullptr, nullptr, klh, kll, wth,
                                                        ob, nullptr, nullptr);
  gemm128<1><<<dim3(256, 4), 256, 0, stream>>>(ob, woutT, nullptr, nullptr, nullptr, b_out, x, out);
}

// Round 16
// 901.725 us; speedup vs baseline: 1.0199x; 1.0056x over previous
//
#include <hip/hip_runtime.h>

#define DEV __device__ __forceinline__

typedef unsigned short u16;
typedef unsigned int   u32;
typedef u16   u16x4 __attribute__((ext_vector_type(4)));
typedef u16   u16x8 __attribute__((ext_vector_type(8)));
typedef __bf16 bf16x8 __attribute__((ext_vector_type(8)));
typedef float f32x4 __attribute__((ext_vector_type(4)));

DEV float b2f(u16 u){ return __uint_as_float(((u32)u) << 16); }
DEV u16 f2b(float f){ u32 u = __float_as_uint(f); u32 r = (u + 0x7fffu + ((u >> 16) & 1u)) >> 16; return (u16)r; }

// RNE triple split: x = h + l + l2 (each bf16), residual ~2^-27 rel
DEV void split3(float x, u16& h, u16& l, u16& l2){
  u32 ub = __float_as_uint(x);
  u32 rb = ub + 0x7fffu + ((ub >> 16) & 1u);
  float hf = __uint_as_float(rb & 0xffff0000u);
  float r1 = x - hf;
  u32 u1 = __float_as_uint(r1);
  u32 rb1 = u1 + 0x7fffu + ((u1 >> 16) & 1u);
  float lf = __uint_as_float(rb1 & 0xffff0000u);
  h = (u16)(rb >> 16);
  l = (u16)(rb1 >> 16);
  l2 = f2b(r1 - lf);
}

DEV f32x4 mfma16(u16x8 a, u16x8 b, f32x4 c){
  return __builtin_amdgcn_mfma_f32_16x16x32_bf16(
      __builtin_bit_cast(bf16x8, a), __builtin_bit_cast(bf16x8, b), c, 0, 0, 0);
}

// async global->LDS 16B (wave-uniform LDS base + lane*16; LDS must be linear)
DEV void gload16(const void* g, void* l){
  __builtin_amdgcn_global_load_lds(
      (const __attribute__((address_space(1))) u32*)g,
      (__attribute__((address_space(3))) u32*)l,
      16, 0, 0);
}

// ---------------- LayerNorm: x(f32) -> xn(bf16) + per-row stats ----------------
__global__ __launch_bounds__(256) void ln_kernel(const float* __restrict__ x,
                                                 const float* __restrict__ w,
                                                 const float* __restrict__ bb,
                                                 u16* __restrict__ xn,
                                                 float2* __restrict__ stats){
  int row = blockIdx.x;
  const float* xr = x + (size_t)row * 512;
  int t = threadIdx.x;
  float2 v = *(const float2*)(xr + t * 2);
  float s = v.x + v.y;
  float sq = v.x * v.x + v.y * v.y;
  #pragma unroll
  for(int off = 32; off; off >>= 1){ s += __shfl_xor(s, off, 64); sq += __shfl_xor(sq, off, 64); }
  __shared__ float rs[4], rq[4];
  int wv = t >> 6, ln = t & 63;
  if(ln == 0){ rs[wv] = s; rq[wv] = sq; }
  __syncthreads();
  s = rs[0] + rs[1] + rs[2] + rs[3];
  sq = rq[0] + rq[1] + rq[2] + rq[3];
  float mu = s * (1.f / 512.f);
  float var = sq * (1.f / 512.f) - mu * mu;
  float rstd = rsqrtf(var + 1e-5f);
  if(t == 0) stats[row] = make_float2(mu, rstd);
  float w0 = w[t * 2], w1 = w[t * 2 + 1], b0 = bb[t * 2], b1 = bb[t * 2 + 1];
  u16 u0 = f2b((v.x - mu) * rstd * w0 + b0);
  u16 u1 = f2b((v.y - mu) * rstd * w1 + b1);
  ((u32*)(xn + (size_t)row * 512))[t] = (u32)u0 | ((u32)u1 << 16);
}

// ------------- landmark means of LN(x) in fp32: xl[b*256+j][512] -------------
__global__ __launch_bounds__(256) void xl_kernel(const float* __restrict__ x,
                                                 const float2* __restrict__ stats,
                                                 const float* __restrict__ w,
                                                 const float* __restrict__ bb,
                                                 float* __restrict__ xl){
  int blk = blockIdx.x;          // b*256 + j
  int b = blk >> 8, j = blk & 255;
  int t = threadIdx.x;
  int d0 = t * 2;
  float acc0 = 0.f, acc1 = 0.f;
  size_t row0 = (size_t)b * 8192 + (size_t)j * 32;
  for(int tt = 0; tt < 32; tt++){
    size_t row = row0 + tt;
    float2 st = stats[row];
    const float* xr = x + row * 512;
    float2 v = *(const float2*)(xr + d0);
    acc0 += (v.x - st.x) * st.y;
    acc1 += (v.y - st.x) * st.y;
  }
  float* dst = xl + (size_t)blk * 512;
  dst[d0]     = acc0 * (1.f / 32.f) * w[d0]     + bb[d0];
  dst[d0 + 1] = acc1 * (1.f / 32.f) * w[d0 + 1] + bb[d0 + 1];
}

// ------------- fused weight prep: wqkvT(bf16), woutT(bf16), wqkT(f32) -------------
__global__ __launch_bounds__(256) void prep_weights(const float* __restrict__ w_qkv,
                                                    const float* __restrict__ w_out,
                                                    u16* __restrict__ wqkvT,
                                                    u16* __restrict__ woutT,
                                                    float* __restrict__ wqkT){
  int idx = blockIdx.x * 256 + threadIdx.x;
  if(idx < 786432){
    int k = idx / 1536, n = idx - k * 1536;
    wqkvT[(size_t)n * 512 + k] = f2b(w_qkv[idx]);
  } else if(idx < 786432 + 262144){
    int i2 = idx - 786432;
    int k = i2 >> 9, n = i2 & 511;
    woutT[(size_t)n * 512 + k] = f2b(w_out[i2]);
  } else {
    int i3 = idx - 786432 - 262144;
    int n = i3 >> 9, k = i3 & 511;
    wqkT[i3] = w_qkv[(size_t)k * 1536 + n];
  }
}

// ------------- v [key][d] -> vt [d][key] (bf16, per bh) -------------
__global__ __launch_bounds__(256) void vtrans_kernel(const u16* __restrict__ v,
                                                     u16* __restrict__ vt){
  __shared__ u16 tile[64][72];
  int bh = blockIdx.y, n0 = blockIdx.x * 64;
  int t = threadIdx.x;
  for(int s = t; s < 512; s += 256){
    int row = s >> 3, col = (s & 7) * 8;
    *(u16x8*)&tile[row][col] = *(const u16x8*)(v + ((size_t)bh * 8192 + n0 + row) * 64 + col);
  }
  __syncthreads();
  for(int s = t; s < 512; s += 256){
    int d = s >> 3, nc = (s & 7) * 8;
    u16x8 u;
    #pragma unroll
    for(int e = 0; e < 8; e++) u[e] = tile[nc + e][d];
    *(u16x8*)(vt + ((size_t)bh * 64 + d) * 8192 + n0 + nc) = u;
  }
}

// ------------- big bf16 GEMM: A[M x 512] @ BT[N x 512]^T, 128x128 tile -------------
// BK=64 (16 barriers/block), XOR-swizzled LDS: linear gload dest + pre-swizzled
// global source col + swizzled fragment read (rule-21 both-sides involution).
template<int EPI>
__global__ __launch_bounds__(256) void gemm128(const u16* __restrict__ A,
                                               const u16* __restrict__ BT,
                                               u16* __restrict__ qo, u16* __restrict__ ko, u16* __restrict__ vo,
                                               const float* __restrict__ bout,
                                               const float* __restrict__ xres,
                                               float* __restrict__ dout){
  __shared__ u16 As[128 * 64];
  __shared__ u16 Bs[128 * 64];
  const int K = 512;
  int nby = gridDim.y;
  int nwg = gridDim.x * nby;
  int orig = blockIdx.y * gridDim.x + blockIdx.x;
  int cpx = nwg >> 3;
  int wg = (orig & 7) * cpx + (orig >> 3);
  int fx = wg / nby, fy = wg - fx * nby;
  int tb_m = fx * 128, tb_n = fy * 128;
  int tid = threadIdx.x, lane = tid & 63, w = tid >> 6;
  int wm = (w >> 1) * 64, wn = (w & 1) * 64;
  f32x4 acc[4][4] = {};
  // staging: thread tid -> LDS physical (row=tid>>3, slot=tid&7); global col
  // pre-swizzled so logical slot = physical ^ (row&7)
  int srow = tid >> 3;
  int sk = (((tid & 7) ^ (srow & 7))) * 8;
  const u16* Ag = A + (size_t)(tb_m + srow) * K + sk;
  const u16* Bg = BT + (size_t)(tb_n + srow) * K + sk;
  u16* Al = As + tid * 8;
  u16* Bl = Bs + tid * 8;
  for(int kk = 0; kk < K; kk += 64){
    __syncthreads();
    gload16(Ag + kk,                    Al);
    gload16(Ag + kk + (size_t)32 * K,   Al + 2048);
    gload16(Ag + kk + (size_t)64 * K,   Al + 4096);
    gload16(Ag + kk + (size_t)96 * K,   Al + 6144);
    gload16(Bg + kk,                    Bl);
    gload16(Bg + kk + (size_t)32 * K,   Bl + 2048);
    gload16(Bg + kk + (size_t)64 * K,   Bl + 4096);
    gload16(Bg + kk + (size_t)96 * K,   Bl + 6144);
    __syncthreads();
    int r = lane & 15, lg = lane >> 4;
    #pragma unroll
    for(int k2 = 0; k2 < 2; k2++){
      u16x8 af[4], bf[4];
      int slotL = k2 * 4 + lg;
      #pragma unroll
      for(int mi = 0; mi < 4; mi++){
        int row = wm + mi * 16 + r;
        af[mi] = *(const u16x8*)&As[row * 64 + ((slotL ^ (row & 7)) * 8)];
      }
      #pragma unroll
      for(int ni = 0; ni < 4; ni++){
        int row = wn + ni * 16 + r;
        bf[ni] = *(const u16x8*)&Bs[row * 64 + ((slotL ^ (row & 7)) * 8)];
      }
      #pragma unroll
      for(int mi = 0; mi < 4; mi++)
        #pragma unroll
        for(int ni = 0; ni < 4; ni++)
          acc[mi][ni] = mfma16(af[mi], bf[ni], acc[mi][ni]);
    }
  }
  int r = lane & 15, rr = (lane >> 4) * 4;
  #pragma unroll
  for(int mi = 0; mi < 4; mi++)
    #pragma unroll
    for(int ni = 0; ni < 4; ni++){
      int col = tb_n + wn + ni * 16 + r;
      #pragma unroll
      for(int e = 0; e < 4; e++){
        int row = tb_m + wm + mi * 16 + rr + e;
        float val = acc[mi][ni][e];
        if(EPI == 0){
          int t3 = col >> 9, h = (col >> 6) & 7, dh = col & 63;
          int b = row >> 13, n = row & 8191;
          if(t3 == 0) val *= 0.125f;
          u16* dst = (t3 == 0 ? qo : (t3 == 1 ? ko : vo));
          dst[(((size_t)(b * 8 + h) * 8192) + n) * 64 + dh] = f2b(val);
        } else {
          val += bout[col] + xres[(size_t)row * 512 + col];
          dout[(size_t)row * 512 + col] = val;
        }
      }
    }
}

// ------------- fp32 GEMM: ql/kl = xl @ wqkT^T, scatter epi + hi/lo split -------------
__global__ __launch_bounds__(256) void gemm_qlkl(const float* __restrict__ A,
                                                 const float* __restrict__ BT,
                                                 float* __restrict__ qlf,
                                                 float* __restrict__ klf,
                                                 u16* __restrict__ qlh, u16* __restrict__ qll,
                                                 u16* __restrict__ klh, u16* __restrict__ kll){
  __shared__ float As[64][17];
  __shared__ float Bs[64][17];
  int tb_m = blockIdx.x * 64, tb_n = blockIdx.y * 64;
  int tid = threadIdx.x;
  int ty = tid >> 4, tx = tid & 15;
  float acc[4][4] = {};
  int srow = tid >> 2, sseg = (tid & 3) * 4;
  const float* Ag = A + (size_t)(tb_m + srow) * 512 + sseg;
  const float* Bg = BT + (size_t)(tb_n + srow) * 512 + sseg;
  for(int kk = 0; kk < 512; kk += 16){
    __syncthreads();
    f32x4 a4 = *(const f32x4*)(Ag + kk);
    f32x4 b4 = *(const f32x4*)(Bg + kk);
    #pragma unroll
    for(int e = 0; e < 4; e++){ As[srow][sseg + e] = a4[e]; Bs[srow][sseg + e] = b4[e]; }
    __syncthreads();
    #pragma unroll
    for(int k2 = 0; k2 < 16; k2++){
      float a[4], b[4];
      #pragma unroll
      for(int i = 0; i < 4; i++) a[i] = As[ty * 4 + i][k2];
      #pragma unroll
      for(int jv = 0; jv < 4; jv++) b[jv] = Bs[tx * 4 + jv][k2];
      #pragma unroll
      for(int i = 0; i < 4; i++)
        #pragma unroll
        for(int jv = 0; jv < 4; jv++) acc[i][jv] += a[i] * b[jv];
    }
  }
  #pragma unroll
  for(int i = 0; i < 4; i++)
    #pragma unroll
    for(int jv = 0; jv < 4; jv++){
      int r = tb_m + ty * 4 + i;
      int c = tb_n + tx * 4 + jv;
      int b = r >> 8, jl = r & 255;
      float val = acc[i][jv];
      if(c < 512){
        float q = val * 0.125f;
        size_t qi = (((size_t)(b * 8 + (c >> 6)) * 256) + jl) * 64 + (c & 63);
        qlf[qi] = q;
        u16 hi = f2b(q);
        qlh[qi] = hi; qll[qi] = f2b(q - b2f(hi));
      } else {
        int c2 = c - 512;
        size_t ki = (((size_t)(b * 8 + (c2 >> 6)) * 256) + jl) * 64 + (c2 & 63);
        klf[ki] = val;
        u16 hi = f2b(val);
        klh[ki] = hi; kll[ki] = f2b(val - b2f(hi));
      }
    }
}

// ------------- batched pinv GEMM via bf16 triple-split MFMA -------------
__global__ __launch_bounds__(256) void gemm_pinv_mfma(
    const u16* __restrict__ Ah, const u16* __restrict__ Al, const u16* __restrict__ Al2,
    const u16* __restrict__ Bh, const u16* __restrict__ Bl, const u16* __restrict__ Bl2,
    u16* __restrict__ Ch, u16* __restrict__ Cl, u16* __restrict__ Cl2,
    float dB, int bneg, float osc){
  __shared__ u16 As_[3][64][40];   // [level][row][k]
  __shared__ u16 Bs_[3][64][40];   // [level][col][k]  (transposed tile)
  int bh = blockIdx.y;
  size_t base = (size_t)bh * 65536;
  int tb_m = (blockIdx.x >> 2) * 64, tb_n = (blockIdx.x & 3) * 64;
  int tid = threadIdx.x, lane = tid & 63, w = tid >> 6;
  int lr = lane & 15, lg = lane >> 4;
  int wm = (w >> 1) * 32, wn = (w & 1) * 32;
  f32x4 acc[2][2] = {};
  int arow = tid >> 2, akq = (tid & 3) * 8;
  int bcol = tid & 63, bkq = tid >> 6;
  u16 sx = bneg ? (u16)0x8000u : (u16)0;
  size_t aoff = base + (size_t)(tb_m + arow) * 256 + akq;
  size_t boff = base + (size_t)(tb_n + bcol);
  for(int kk = 0; kk < 256; kk += 32){
    u16x8 ra0 = *(const u16x8*)(Ah + aoff + kk);
    u16x8 ra1 = *(const u16x8*)(Al + aoff + kk);
    u16x8 ra2 = *(const u16x8*)(Al2 + aoff + kk);
    u16x8 rb0, rb1, rb2;
    #pragma unroll
    for(int j = 0; j < 8; j++){
      size_t bi = boff + (size_t)(kk + bkq * 8 + j) * 256;
      rb0[j] = Bh[bi] ^ sx;
      rb1[j] = Bl[bi] ^ sx;
      rb2[j] = Bl2[bi] ^ sx;
    }
    __syncthreads();
    *(u16x8*)&As_[0][arow][akq] = ra0;
    *(u16x8*)&As_[1][arow][akq] = ra1;
    *(u16x8*)&As_[2][arow][akq] = ra2;
    *(u16x8*)&Bs_[0][bcol][bkq * 8] = rb0;
    *(u16x8*)&Bs_[1][bcol][bkq * 8] = rb1;
    *(u16x8*)&Bs_[2][bcol][bkq * 8] = rb2;
    __syncthreads();
    u16x8 af[3][2], bf[3][2];
    #pragma unroll
    for(int v = 0; v < 3; v++)
      #pragma unroll
      for(int mi = 0; mi < 2; mi++){
        af[v][mi] = *(const u16x8*)&As_[v][wm + mi * 16 + lr][lg * 8];
        bf[v][mi] = *(const u16x8*)&Bs_[v][wn + mi * 16 + lr][lg * 8];
      }
    #pragma unroll
    for(int mi = 0; mi < 2; mi++)
      #pragma unroll
      for(int ni = 0; ni < 2; ni++){
        acc[mi][ni] = mfma16(af[1][mi], bf[1][ni], acc[mi][ni]);   // l*l
        acc[mi][ni] = mfma16(af[2][mi], bf[0][ni], acc[mi][ni]);   // l2*h
        acc[mi][ni] = mfma16(af[0][mi], bf[2][ni], acc[mi][ni]);   // h*l2
        acc[mi][ni] = mfma16(af[1][mi], bf[0][ni], acc[mi][ni]);   // l*h
        acc[mi][ni] = mfma16(af[0][mi], bf[1][ni], acc[mi][ni]);   // h*l
        acc[mi][ni] = mfma16(af[0][mi], bf[0][ni], acc[mi][ni]);   // h*h
      }
  }
  #pragma unroll
  for(int mi = 0; mi < 2; mi++)
    #pragma unroll
    for(int ni = 0; ni < 2; ni++)
      #pragma unroll
      for(int e = 0; e < 4; e++){
        int r = tb_m + wm + mi * 16 + lg * 4 + e;
        int c = tb_n + wn + ni * 16 + lr;
        size_t idx = base + (size_t)r * 256 + c;
        float arec = b2f(Ah[idx]) + b2f(Al[idx]) + b2f(Al2[idx]);
        float val = osc * (dB * arec + acc[mi][ni][e]);
        u16 h, l, l2;
        split3(val, h, l, l2);
        Ch[idx] = h; Cl[idx] = l; Cl2[idx] = l2;
      }
}

// ------------- a2 = softmax(q_l @ k_l^T) per row, fp32 + triple -------------
__global__ __launch_bounds__(256) void a2_kernel(const float* __restrict__ qlf,
                                                 const float* __restrict__ klf,
                                                 float* __restrict__ a2,
                                                 u16* __restrict__ a2h, u16* __restrict__ a2l,
                                                 u16* __restrict__ a2l2){
  int i = blockIdx.x, bh = blockIdx.y, j = threadIdx.x;
  const float* qp = qlf + ((size_t)bh * 256 + i) * 64;
  const float* kp = klf + ((size_t)bh * 256 + j) * 64;
  float s = 0.f;
  #pragma unroll
  for(int d0 = 0; d0 < 16; d0++){
    f32x4 uq = *(const f32x4*)(qp + d0 * 4);
    f32x4 uk = *(const f32x4*)(kp + d0 * 4);
    #pragma unroll
    for(int e = 0; e < 4; e++) s += uq[e] * uk[e];
  }
  __shared__ float red[256];
  red[j] = s; __syncthreads();
  for(int off = 128; off; off >>= 1){ if(j < off) red[j] = fmaxf(red[j], red[j + off]); __syncthreads(); }
  float m = red[0]; __syncthreads();
  float p = expf(s - m);
  red[j] = p; __syncthreads();
  for(int off = 128; off; off >>= 1){ if(j < off) red[j] += red[j + off]; __syncthreads(); }
  float denom = red[0];
  float vv = p / denom;
  size_t idx = ((size_t)bh * 256 + i) * 256 + j;
  a2[idx] = vv;
  u16 h, l, l2;
  split3(vv, h, l, l2);
  a2h[idx] = h; a2l[idx] = l; a2l2[idx] = l2;
}

// ------------- scale maxes -------------
__global__ __launch_bounds__(256) void scale_kernel(const float* __restrict__ a2, u32* __restrict__ maxes){
  int bh = blockIdx.x, t = threadIdx.x;
  const float* p = a2 + (size_t)bh * 65536;
  float cs = 0.f, rs = 0.f;
  for(int i = 0; i < 256; i++) cs += p[i * 256 + t];
  for(int j = 0; j < 256; j++) rs += p[t * 256 + j];
  __shared__ float rc[256], rr[256];
  rc[t] = cs; rr[t] = rs; __syncthreads();
  for(int off = 128; off; off >>= 1){
    if(t < off){ rc[t] = fmaxf(rc[t], rc[t + off]); rr[t] = fmaxf(rr[t], rr[t + off]); }
    __syncthreads();
  }
  if(t == 0){
    atomicMax(&maxes[0], __float_as_uint(rc[0]));
    atomicMax(&maxes[1], __float_as_uint(rr[0]));
  }
}

// ------------- z0 = a2^T / scale -> triple (tiled transpose) -------------
__global__ __launch_bounds__(256) void z0_kernel(const float* __restrict__ a2,
                                                 u16* __restrict__ zh, u16* __restrict__ zl,
                                                 u16* __restrict__ zl2,
                                                 const u32* __restrict__ maxes){
  __shared__ float tile[64][65];
  float inv = 1.f / (__uint_as_float(maxes[0]) * __uint_as_float(maxes[1]));
  int bh = blockIdx.z;
  int i0 = blockIdx.x * 64, j0 = blockIdx.y * 64;
  const float* src = a2 + (size_t)bh * 65536;
  size_t dbase = (size_t)bh * 65536;
  for(int s = threadIdx.x; s < 1024; s += 256){
    int r = s >> 4, c4 = (s & 15) * 4;
    f32x4 v = *(const f32x4*)(src + (size_t)(i0 + r) * 256 + j0 + c4);
    #pragma unroll
    for(int e = 0; e < 4; e++) tile[r][c4 + e] = v[e];
  }
  __syncthreads();
  for(int s = threadIdx.x; s < 1024; s += 256){
    int jr = s >> 4, c4 = (s & 15) * 4;
    u16x4 hv, lv, l2v;
    #pragma unroll
    for(int e = 0; e < 4; e++){
      float val = tile[c4 + e][jr] * inv;
      u16 h, l, l2;
      split3(val, h, l, l2);
      hv[e] = h; lv[e] = l; l2v[e] = l2;
    }
    size_t doff = dbase + (size_t)(j0 + jr) * 256 + i0 + c4;
    *(u16x4*)(zh + doff) = hv;
    *(u16x4*)(zl + doff) = lv;
    *(u16x4*)(zl2 + doff) = l2v;
  }
}

// ------------- unified MFMA flash attention, LDS-staged K/V, single-chain PV -------------
// MODE 0 (a1): A=qb exact; B=kl hi/lo; V=W hi only; 256 keys; RMW into o.  smem 45568 B
// MODE 1 (a3v): A=ql hi/lo; B=kb exact; V=v^T exact; 512-key split.        smem 36352 B
template<int MODE>
__global__ __launch_bounds__(256) void flash_kernel(
    const u16* __restrict__ Aex,
    const u16* __restrict__ Ah_, const u16* __restrict__ Al_,
    const u16* __restrict__ Bh_, const u16* __restrict__ Bl_,
    const u16* __restrict__ Vh_,
    u16* __restrict__ o,
    float* __restrict__ pacc, float* __restrict__ plo){
  extern __shared__ char smem[];
  u32 (*pbuf)[32][35] = (u32(*)[32][35])smem;                  // 17920 B; stores P-hi (low16)
  u16 (*ksh)[72] = (u16(*)[72])(smem + 17920);                 // [64][72] key-major
  u16 (*vsh)[72] = (u16(*)[72])(smem + 17920 + 9216);          // [64][72] d-major
  u16 (*ksl)[72] = (u16(*)[72])(smem + 17920 + 2 * 9216);      // MODE0 only

  int tid = threadIdx.x;
  int w = tid >> 6, lane = tid & 63;
  int lr = lane & 15, lg = lane >> 4;
  int bh = blockIdx.y;
  int rowbase = blockIdx.x * 128 + w * 32;
  constexpr int NT = (MODE == 0) ? 4 : 8;
  int kbase = (MODE == 0) ? 0 : blockIdx.z * 512;
  int srow = tid >> 2, sseg = (tid & 3) * 16;

  u16x8 afh[2][2], afl[2][2];
  #pragma unroll
  for(int mi = 0; mi < 2; mi++)
    #pragma unroll
    for(int ks = 0; ks < 2; ks++){
      int r = rowbase + mi * 16 + lr;
      if(MODE == 0){
        afh[mi][ks] = *(const u16x8*)(Aex + ((size_t)bh * 8192 + r) * 64 + ks * 32 + lg * 8);
      } else {
        size_t idx = ((size_t)bh * 256 + r) * 64 + ks * 32 + lg * 8;
        afh[mi][ks] = *(const u16x8*)(Ah_ + idx);
        afl[mi][ks] = *(const u16x8*)(Al_ + idx);
      }
    }

  f32x4 pv[2][4] = {};
  float l[2][4] = {};

  for(int t = 0; t < NT; t++){
    int koff = t * 64;
    __syncthreads();
    if(MODE == 0){
      size_t kix = ((size_t)bh * 256 + koff + srow) * 64 + sseg;
      *(u16x8*)&ksh[srow][sseg]     = *(const u16x8*)(Bh_ + kix);
      *(u16x8*)&ksh[srow][sseg + 8] = *(const u16x8*)(Bh_ + kix + 8);
      *(u16x8*)&ksl[srow][sseg]     = *(const u16x8*)(Bl_ + kix);
      *(u16x8*)&ksl[srow][sseg + 8] = *(const u16x8*)(Bl_ + kix + 8);
      size_t vix = ((size_t)bh * 64 + srow) * 256 + koff + sseg;
      *(u16x8*)&vsh[srow][sseg]     = *(const u16x8*)(Vh_ + vix);
      *(u16x8*)&vsh[srow][sseg + 8] = *(const u16x8*)(Vh_ + vix + 8);
    } else {
      size_t kix = ((size_t)bh * 8192 + kbase + koff + srow) * 64 + sseg;
      *(u16x8*)&ksh[srow][sseg]     = *(const u16x8*)(Bh_ + kix);
      *(u16x8*)&ksh[srow][sseg + 8] = *(const u16x8*)(Bh_ + kix + 8);
      size_t vix = ((size_t)bh * 64 + srow) * 8192 + kbase + koff + sseg;
      *(u16x8*)&vsh[srow][sseg]     = *(const u16x8*)(Vh_ + vix);
      *(u16x8*)&vsh[srow][sseg + 8] = *(const u16x8*)(Vh_ + vix + 8);
    }
    __syncthreads();
    #pragma unroll
    for(int half = 0; half < 2; half++){
      u16x8 bfh[2][2], bfl[2][2];
      #pragma unroll
      for(int ni = 0; ni < 2; ni++){
        int krow = half * 32 + ni * 16 + lr;
        #pragma unroll
        for(int ks = 0; ks < 2; ks++){
          bfh[ni][ks] = *(const u16x8*)&ksh[krow][ks * 32 + lg * 8];
          if(MODE == 0) bfl[ni][ks] = *(const u16x8*)&ksl[krow][ks * 32 + lg * 8];
        }
      }
      f32x4 sv[2][2];
      #pragma unroll
      for(int mi = 0; mi < 2; mi++)
        #pragma unroll
        for(int ni = 0; ni < 2; ni++) sv[mi][ni] = (f32x4){0.f, 0.f, 0.f, 0.f};
      __builtin_amdgcn_s_setprio(1);
      #pragma unroll
      for(int ks = 0; ks < 2; ks++)
        #pragma unroll
        for(int mi = 0; mi < 2; mi++)
          #pragma unroll
          for(int ni = 0; ni < 2; ni++){
            sv[mi][ni] = mfma16(afh[mi][ks], bfh[ni][ks], sv[mi][ni]);
            if(MODE == 0) sv[mi][ni] = mfma16(afh[mi][ks], bfl[ni][ks], sv[mi][ni]);
            else          sv[mi][ni] = mfma16(afl[mi][ks], bfh[ni][ks], sv[mi][ni]);
          }
      __builtin_amdgcn_s_setprio(0);
      // exp + per-lane l; store P-hi into pbuf (transpose)
      #pragma unroll
      for(int mi = 0; mi < 2; mi++)
        #pragma unroll
        for(int ni = 0; ni < 2; ni++)
          #pragma unroll
          for(int e = 0; e < 4; e++){
            float p = __expf(sv[mi][ni][e]);
            l[mi][e] += p;
            u32 pb = __float_as_uint(p);
            u32 rb = pb + 0x7fffu + ((pb >> 16) & 1u);
            pbuf[w][mi * 16 + lg * 4 + e][ni * 16 + lr] = rb >> 16;
          }
      u16x8 pah[2];
      #pragma unroll
      for(int mi = 0; mi < 2; mi++){
        u32 tv[8];
        #pragma unroll
        for(int e2 = 0; e2 < 8; e2++) tv[e2] = pbuf[w][mi * 16 + lr][lg * 8 + e2];
        u32* ph = (u32*)&pah[mi];
        #pragma unroll
        for(int q = 0; q < 4; q++)
          ph[q] = __builtin_amdgcn_perm(tv[2 * q + 1], tv[2 * q], 0x05040100u);
      }
      __builtin_amdgcn_s_setprio(1);
      #pragma unroll
      for(int ni2 = 0; ni2 < 4; ni2++){
        int d = ni2 * 16 + lr;
        u16x8 vh = *(const u16x8*)&vsh[d][half * 32 + lg * 8];
        #pragma unroll
        for(int mi = 0; mi < 2; mi++)
          pv[mi][ni2] = mfma16(pah[mi], vh, pv[mi][ni2]);
      }
      __builtin_amdgcn_s_setprio(0);
    }
  }
  #pragma unroll
  for(int mi = 0; mi < 2; mi++)
    #pragma unroll
    for(int e = 0; e < 4; e++){
      float lv = l[mi][e];
      #pragma unroll
      for(int off = 1; off < 16; off <<= 1) lv += __shfl_xor(lv, off, 64);
      l[mi][e] = lv;
    }
  #pragma unroll
  for(int mi = 0; mi < 2; mi++){
    #pragma unroll
    for(int e = 0; e < 4; e++){
      int row = rowbase + mi * 16 + lg * 4 + e;
      if(MODE == 0){
        float invl = 1.f / l[mi][e];
        int b = bh >> 3, h = bh & 7;
        #pragma unroll
        for(int ni2 = 0; ni2 < 4; ni2++){
          int col = ni2 * 16 + lr;
          size_t oi = ((size_t)b * 8192 + row) * 512 + h * 64 + col;
          o[oi] = f2b(pv[mi][ni2][e] * invl + b2f(o[oi]));
        }
      } else {
        #pragma unroll
        for(int ni2 = 0; ni2 < 4; ni2++){
          int col = ni2 * 16 + lr;
          pacc[(((size_t)blockIdx.z * 8192) + (size_t)bh * 256 + row) * 64 + col] = pv[mi][ni2][e];
        }
      }
    }
  }
  if(MODE == 1 && lr == 0){
    #pragma unroll
    for(int mi = 0; mi < 2; mi++)
      #pragma unroll
      for(int e = 0; e < 4; e++){
        int row = rowbase + mi * 16 + lg * 4 + e;
        plo[(size_t)blockIdx.z * 8192 + (size_t)bh * 256 + row] = l[mi][e];
      }
  }
}

// ------------- merge a3v split-K partials (16) -> av fp32 -------------
__global__ __launch_bounds__(64) void a3v_merge(const float* __restrict__ pacc,
                                                const float* __restrict__ plo,
                                                float* __restrict__ av){
  int row = blockIdx.x, d = threadIdx.x;
  float L = 0.f, acc = 0.f;
  #pragma unroll
  for(int p = 0; p < 16; p++){
    L += plo[(size_t)p * 8192 + row];
    acc += pacc[((size_t)p * 8192 + row) * 64 + d];
  }
  av[(size_t)row * 64 + d] = acc / L;
}

// ------------- W^T = (Z @ av)^T as bf16 (hi only); Z from triple -------------
__global__ __launch_bounds__(64) void zw_kernel(const u16* __restrict__ zh,
                                                const u16* __restrict__ zl,
                                                const u16* __restrict__ zl2,
                                                const float* __restrict__ av,
                                                u16* __restrict__ wth){
  int i = blockIdx.x & 255, bh = blockIdx.x >> 8, d = threadIdx.x;
  size_t zr = ((size_t)bh * 256 + i) * 256;
  const float* ab = av + (size_t)bh * 256 * 64;
  float s = 0.f;
  for(int j8 = 0; j8 < 32; j8++){
    u16x8 hv = *(const u16x8*)(zh + zr + j8 * 8);
    u16x8 lv = *(const u16x8*)(zl + zr + j8 * 8);
    u16x8 l2v = *(const u16x8*)(zl2 + zr + j8 * 8);
    #pragma unroll
    for(int e = 0; e < 8; e++){
      float zv = b2f(hv[e]) + b2f(lv[e]) + b2f(l2v[e]);
      s += zv * ab[(j8 * 8 + e) * 64 + d];
    }
  }
  wth[((size_t)bh * 64 + d) * 256 + i] = f2b(s);
}

// ------------- depthwise conv residual -> o (bf16 token layout), register-blocked -------------
__global__ __launch_bounds__(256) void conv_kernel(const u16* __restrict__ v,
                                                   const float* __restrict__ cw,
                                                   u16* __restrict__ o){
  __shared__ float wl[33];
  __shared__ float vt[64][104];
  int bh = blockIdx.y, b = bh >> 3, h = bh & 7;
  int r0 = blockIdx.x * 64;
  if(threadIdx.x < 33) wl[threadIdx.x] = cw[h * 33 + threadIdx.x];
  const u16* vb = v + (size_t)bh * 8192 * 64;
  for(int idx = threadIdx.x; idx < 768; idx += 256){
    int row = idx >> 3, c8 = (idx & 7) * 8;
    int gr = r0 - 16 + row;
    u16x8 u = {};
    if(gr >= 0 && gr < 8192) u = *(const u16x8*)(vb + (size_t)gr * 64 + c8);
    #pragma unroll
    for(int e = 0; e < 8; e++) vt[c8 + e][row] = b2f(u[e]);
  }
  __syncthreads();
  int d = threadIdx.x & 63, g = threadIdx.x >> 6;
  float vin[48];
  #pragma unroll
  for(int i = 0; i < 12; i++){
    f32x4 q4 = *(const f32x4*)&vt[d][g * 16 + i * 4];
    #pragma unroll
    for(int e = 0; e < 4; e++) vin[i * 4 + e] = q4[e];
  }
  float acc[16] = {};
  #pragma unroll
  for(int t = 0; t < 33; t++){
    float wt = wl[t];
    #pragma unroll
    for(int r = 0; r < 16; r++) acc[r] += wt * vin[r + t];
  }
  #pragma unroll
  for(int r = 0; r < 16; r++){
    size_t oi = ((size_t)b * 8192 + (r0 + g * 16 + r)) * 512 + h * 64 + d;
    o[oi] = f2b(acc[r]);
  }
}

extern "C" void kernel_launch(void* const* d_in, const int* in_sizes, int n_in,
                              void* d_out, int out_size, void* d_ws, size_t ws_size,
                              hipStream_t stream){
  (void)in_sizes; (void)n_in; (void)out_size; (void)ws_size;
  const float* x     = (const float*)d_in[0];
  const float* ln_w  = (const float*)d_in[1];
  const float* ln_b  = (const float*)d_in[2];
  const float* w_qkv = (const float*)d_in[3];
  const float* w_out = (const float*)d_in[4];
  const float* b_out = (const float*)d_in[5];
  const float* cw    = (const float*)d_in[6];
  float* out = (float*)d_out;

  char* base = (char*)d_ws;
  size_t off = 0;
  auto alloc = [&](size_t bytes)->void*{
    void* r = base + off; off += (bytes + 255) & ~(size_t)255; return r;
  };
  const size_t MSZ = 32ull * 65536 * 2;  // one bf16 matrix level: 4,194,304 B
  u16* xn      = (u16*)alloc(32768ull * 512 * 2);   // LN out; pinv: az+x2 triples; later pacc; later ob
  float2* stat = (float2*)alloc(32768ull * 8);
  u16* qb      = (u16*)alloc(32ull * 8192 * 64 * 2);
  u16* kb      = (u16*)alloc(32ull * 8192 * 64 * 2);
  u16* vb      = (u16*)alloc(32ull * 8192 * 64 * 2);
  u16* vtb     = (u16*)alloc(32ull * 8192 * 64 * 2);
  u16* wqkvT   = (u16*)alloc(1536ull * 512 * 2);
  u16* woutT   = (u16*)alloc(512ull * 512 * 2);
  // contiguous scratch region (dead during pinv) hosting x3 triple:
  float* wqkT  = (float*)alloc(1024ull * 512 * 4);
  float* xl    = (float*)alloc(1024ull * 512 * 4);
  float* qlf   = (float*)alloc(32ull * 256 * 64 * 4);
  float* klf   = (float*)alloc(32ull * 256 * 64 * 4);
  float* a2b   = (float*)alloc(32ull * 65536 * 4);
  // ---
  u16* qlh     = (u16*)alloc(32ull * 256 * 64 * 2);
  u16* qll     = (u16*)alloc(32ull * 256 * 64 * 2);
  u16* klh     = (u16*)alloc(32ull * 256 * 64 * 2);
  u16* kll     = (u16*)alloc(32ull * 256 * 64 * 2);
  u16* a2th    = (u16*)alloc(MSZ);
  u16* a2tl    = (u16*)alloc(MSZ);
  u16* a2tl2   = (u16*)alloc(MSZ);
  u16* zAh     = (u16*)alloc(MSZ);
  u16* zAl     = (u16*)alloc(MSZ);
  u16* zAl2    = (u16*)alloc(MSZ);
  u16* zBh     = (u16*)alloc(MSZ);
  u16* zBl     = (u16*)alloc(MSZ);
  u16* zBl2    = (u16*)alloc(MSZ);
  float* av    = (float*)alloc(32ull * 256 * 64 * 4);
  u16* wth     = (u16*)alloc(32ull * 64 * 256 * 2);
  u32* scal    = (u32*)alloc(256);
  u16* ob = xn;
  // aliases (live only during pinv loop):
  u16* azh  = xn;
  u16* azl  = (u16*)((char*)xn + MSZ);
  u16* azl2 = (u16*)((char*)xn + 2 * MSZ);
  u16* x2h  = (u16*)((char*)xn + 3 * MSZ);
  u16* x2l  = (u16*)((char*)xn + 4 * MSZ);
  u16* x2l2 = (u16*)((char*)xn + 5 * MSZ);
  u16* x3h  = (u16*)wqkT;
  u16* x3l  = (u16*)((char*)wqkT + MSZ);
  u16* x3l2 = (u16*)((char*)wqkT + 2 * MSZ);
  float* pacc = (float*)xn;
  float* plo  = (float*)wqkT;

  hipMemsetAsync(scal, 0, 8, stream);
  ln_kernel<<<32768, 256, 0, stream>>>(x, ln_w, ln_b, xn, stat);
  prep_weights<<<6144, 256, 0, stream>>>(w_qkv, w_out, wqkvT, woutT, wqkT);
  gemm128<0><<<dim3(256, 12), 256, 0, stream>>>(xn, wqkvT, qb, kb, vb, nullptr, nullptr, nullptr);
  vtrans_kernel<<<dim3(128, 32), 256, 0, stream>>>(vb, vtb);
  xl_kernel<<<1024, 256, 0, stream>>>(x, stat, ln_w, ln_b, xl);
  gemm_qlkl<<<dim3(16, 16), 256, 0, stream>>>(xl, wqkT, qlf, klf, qlh, qll, klh, kll);
  a2_kernel<<<dim3(256, 32), 256, 0, stream>>>(qlf, klf, a2b, a2th, a2tl, a2tl2);
  scale_kernel<<<32, 256, 0, stream>>>(a2b, scal);
  z0_kernel<<<dim3(4, 4, 32), 256, 0, stream>>>(a2b, zAh, zAl, zAl2, scal);

  u16* zPh = zAh; u16* zPl = zAl; u16* zPl2 = zAl2;
  u16* zQh = zBh; u16* zQl = zBl; u16* zQl2 = zBl2;
  for(int it = 0; it < 6; it++){
    gemm_pinv_mfma<<<dim3(16, 32), 256, 0, stream>>>(a2th, a2tl, a2tl2, zPh, zPl, zPl2,
                                                     azh, azl, azl2, 0.f, 0, 1.f);
    gemm_pinv_mfma<<<dim3(16, 32), 256, 0, stream>>>(azh, azl, azl2, azh, azl, azl2,
                                                     x2h, x2l, x2l2, 7.f, 1, 1.f);
    gemm_pinv_mfma<<<dim3(16, 32), 256, 0, stream>>>(azh, azl, azl2, x2h, x2l, x2l2,
                                                     x3h, x3l, x3l2, 11.f, 1, 1.f);
    gemm_pinv_mfma<<<dim3(16, 32), 256, 0, stream>>>(zPh, zPl, zPl2, x3h, x3l, x3l2,
                                                     zQh, zQl, zQl2, 13.f, 1, 0.25f);
    u16* t;
    t = zPh; zPh = zQh; zQh = t;
    t = zPl; zPl = zQl; zQl = t;
    t = zPl2; zPl2 = zQl2; zQl2 = t;
  }

  flash_kernel<1><<<dim3(2, 32, 16), 256, 36352, stream>>>(nullptr, qlh, qll, kb, nullptr, vtb,
                                                           nullptr, pacc, plo);
  a3v_merge<<<8192, 64, 0, stream>>>(pacc, plo, av);
  zw_kernel<<<8192, 64, 0, stream>>>(zPh, zPl, zPl2, av, wth);
  conv_kernel<<<dim3(128, 32), 256, 0, stream>>>(vb, cw, ob);
  flash_kernel<0><<<dim3(64, 32), 256, 45568, stream>>>(qb, nullptr, nullptr, klh, kll, wth,
                                                        ob, nullptr, nullptr);
  gemm128<1><<<dim3(256, 4), 256, 0, stream>>>(ob, woutT, nullptr, nullptr, nullptr, b_out, x, out);
}